// Round 7
// baseline (1241.194 us; speedup 1.0000x reference)
//
#include <hip/hip_runtime.h>

typedef __attribute__((ext_vector_type(4))) float floatx4;
typedef __attribute__((ext_vector_type(8))) _Float16 half8;

// ---------- fp16 helpers (RNE via _Float16 convert) ----------
union H2 { unsigned int u; _Float16 h[2]; };

__device__ __forceinline__ float hs2f(unsigned short u) {
    union { unsigned short u; _Float16 h; } c; c.u = u; return (float)c.h;
}
__device__ __forceinline__ unsigned short f2hs(float f) {
    union { unsigned short u; _Float16 h; } c; c.h = (_Float16)f; return c.u;
}
__device__ __forceinline__ unsigned int pack2h(float a, float b) {
    H2 c; c.h[0] = (_Float16)a; c.h[1] = (_Float16)b; return c.u;
}

// ---------- async global->LDS, 16B per lane ----------
__device__ __forceinline__ void load_lds16(const unsigned short* g, unsigned short* l) {
    __builtin_amdgcn_global_load_lds(
        (__attribute__((address_space(1))) void*)(g),
        (__attribute__((address_space(3))) void*)(l), 16, 0, 0);
}

// ---------- CSR build ----------
__global__ void k_hist(const int* __restrict__ dst, const int* __restrict__ et,
                       int* __restrict__ cnt4, int E) {
    int i = blockIdx.x * 256 + threadIdx.x;
    if (i < E) {
        atomicAdd(&cnt4[dst[i] * 4 + et[i]], 1);
    }
}

__global__ void k_scan_blk(const int* __restrict__ cnt4, int* __restrict__ row_ptr,
                           int* __restrict__ bsum, int N) {
    __shared__ int sm[256];
    int b = blockIdx.x, t = threadIdx.x, i = b * 256 + t;
    int v = 0;
    if (i < N) {
        const int4 q = ((const int4*)cnt4)[i];
        v = q.x + q.y + q.z + q.w;
    }
    sm[t] = v;
    __syncthreads();
    for (int off = 1; off < 256; off <<= 1) {
        int x = (t >= off) ? sm[t - off] : 0;
        __syncthreads();
        sm[t] += x;
        __syncthreads();
    }
    if (i < N) row_ptr[i] = sm[t] - v;
    if (t == 255) bsum[b] = sm[255];
}

__global__ void k_scan_top(int* __restrict__ bsum, int* __restrict__ boff,
                           int* __restrict__ row_ptr, int nblocks, int N) {
    __shared__ int sm[256];
    int t = threadIdx.x;
    int v = (t < nblocks) ? bsum[t] : 0;
    sm[t] = v;
    __syncthreads();
    for (int off = 1; off < 256; off <<= 1) {
        int x = (t >= off) ? sm[t - off] : 0;
        __syncthreads();
        sm[t] += x;
        __syncthreads();
    }
    if (t < nblocks) boff[t] = sm[t] - v;
    if (t == 255) row_ptr[N] = sm[255];
}

// per-(dst,type) segment cursors: cursor4[v][t] = row_ptr[v] + prefix(cnt4[v][0..t-1])
__global__ void k_scan_add(int* __restrict__ row_ptr, int* __restrict__ cursor4,
                           const int* __restrict__ boff, const int* __restrict__ cnt4, int N) {
    int i = blockIdx.x * 256 + threadIdx.x;
    if (i < N) {
        int r = row_ptr[i] + boff[blockIdx.x];
        row_ptr[i] = r;
        const int4 q = ((const int4*)cnt4)[i];
        int4 c;
        c.x = r;
        c.y = r + q.x;
        c.z = r + q.x + q.y;
        c.w = r + q.x + q.y + q.z;
        ((int4*)cursor4)[i] = c;
    }
}

// edges sorted by (dst, etype): segment pick in aggregate is wave-uniform scalar.
__global__ void k_scatter(const int* __restrict__ src, const int* __restrict__ dst,
                          const int* __restrict__ et, int* __restrict__ cursor4,
                          int* __restrict__ edge_pk, int E) {
    int i = blockIdx.x * 256 + threadIdx.x;
    if (i < E) {
        int p = atomicAdd(&cursor4[dst[i] * 4 + et[i]], 1);
        edge_pk[p] = src[i];
    }
}

// ---------- init h (fp16) into AH[:,128:256] ----------
__global__ void k_init_h(const float* __restrict__ feat, unsigned short* __restrict__ AH, int N) {
    int i = blockIdx.x * 256 + threadIdx.x;
    if (i < N * 128) {
        int v = i >> 7, d = i & 127;
        AH[(size_t)v * 256 + 128 + d] = f2hs(feat[i]);
    }
}

// ---------- weight prep: single fp16, n-major [Nout][K] ----------
__global__ void k_prep_wcat(const float* __restrict__ W, unsigned short* __restrict__ w) {
    int i = blockIdx.x * 256 + threadIdx.x;   // 4*128*128 = 65536
    if (i < 65536) {
        int t = i >> 14, o = (i >> 7) & 127, d = i & 127;
        w[o * 512 + t * 128 + d] = f2hs(W[i]);
    }
}

// r,z rows: Wrz[256][256], row j = [W_ih[j] | W_hh[j]]
__global__ void k_prep_wrz(const float* __restrict__ Wih, const float* __restrict__ Whh,
                           unsigned short* __restrict__ w) {
    int i = blockIdx.x * 256 + threadIdx.x;   // 256*256
    if (i < 256 * 256) {
        int j = i >> 8, k = i & 255;
        float v = (k < 128) ? Wih[j * 128 + k] : Whh[j * 128 + (k - 128)];
        w[i] = f2hs(v);
    }
}

// i_n rows: Win[128][128] = W_ih rows 256..383 ; h_n rows: Whn[128][128] = W_hh rows 256..383
__global__ void k_prep_wnh(const float* __restrict__ Wih, const float* __restrict__ Whh,
                           unsigned short* __restrict__ win, unsigned short* __restrict__ whn) {
    int i = blockIdx.x * 256 + threadIdx.x;   // 128*128
    if (i < 128 * 128) {
        int c = i >> 7, k = i & 127;
        win[i] = f2hs(Wih[(256 + c) * 128 + k]);
        whn[i] = f2hs(Whh[(256 + c) * 128 + k]);
    }
}

// ---------- per-step: aggregate h[src] by (dst, etype): S[v][t*128+d] ----------
// TWO adjacent nodes per wave over one contiguous edge range; 12-deep clamped
// batches; segment pick = wave-uniform scalar compare tree. Near the mixed
// L2/L3 service-rate ceiling (~5.4 TB/s effective) -- micro-opts neutral (R5).
__global__ __launch_bounds__(256) void k_aggregate(
    const int* __restrict__ row_ptr, const int* __restrict__ cnt4,
    const int* __restrict__ edge_pk,
    const unsigned short* __restrict__ AH, unsigned short* __restrict__ S, int N)
{
    const int wv = threadIdx.x >> 6;
    const int lane = threadIdx.x & 63;
    const int v0 = blockIdx.x * 8 + wv * 2;
    if (v0 >= N) return;
    const int v1 = v0 + 1;
    const bool has1 = (v1 < N);

    const int beg0 = __builtin_amdgcn_readfirstlane(row_ptr[v0]);
    const int end0 = __builtin_amdgcn_readfirstlane(row_ptr[v0 + 1]);
    const int end1 = has1 ? __builtin_amdgcn_readfirstlane(row_ptr[v1 + 1]) : end0;
    const int4 q0 = ((const int4*)cnt4)[v0];
    const int c1 = beg0 + __builtin_amdgcn_readfirstlane(q0.x);
    const int c2 = c1 + __builtin_amdgcn_readfirstlane(q0.y);
    const int c3 = c2 + __builtin_amdgcn_readfirstlane(q0.z);
    const int c4 = end0;
    int c5 = end0, c6 = end0, c7 = end0;
    if (has1) {
        const int4 q1 = ((const int4*)cnt4)[v1];
        c5 = end0 + __builtin_amdgcn_readfirstlane(q1.x);
        c6 = c5 + __builtin_amdgcn_readfirstlane(q1.y);
        c7 = c6 + __builtin_amdgcn_readfirstlane(q1.z);
    }

    float a0x=0,a0y=0,a1x=0,a1y=0,a2x=0,a2y=0,a3x=0,a3y=0;
    float a4x=0,a4y=0,a5x=0,a5y=0,a6x=0,a6y=0,a7x=0,a7y=0;
    const unsigned short* hbase = AH + 128 + lane * 2;

    for (int e = beg0; e < end1; e += 12) {
        int sp[12];
        unsigned int hv[12];
#pragma unroll
        for (int u = 0; u < 12; ++u) {
            int idx = e + u;
            if (idx > end1 - 1) idx = end1 - 1;
            sp[u] = edge_pk[idx];
        }
#pragma unroll
        for (int u = 0; u < 12; ++u)
            hv[u] = *(const unsigned int*)(hbase + (size_t)sp[u] * 256);
#pragma unroll
        for (int u = 0; u < 12; ++u) {
            const int idx = e + u;              // wave-uniform
            if (idx < end1) {
                H2 c; c.u = hv[u];
                float x0 = (float)c.h[0];
                float x1 = (float)c.h[1];
                if (idx < c4) {
                    if (idx < c2) { if (idx < c1) { a0x+=x0; a0y+=x1; } else { a1x+=x0; a1y+=x1; } }
                    else          { if (idx < c3) { a2x+=x0; a2y+=x1; } else { a3x+=x0; a3y+=x1; } }
                } else {
                    if (idx < c6) { if (idx < c5) { a4x+=x0; a4y+=x1; } else { a5x+=x0; a5y+=x1; } }
                    else          { if (idx < c7) { a6x+=x0; a6y+=x1; } else { a7x+=x0; a7y+=x1; } }
                }
            }
        }
    }

    unsigned int* Sp0 = (unsigned int*)&S[(size_t)v0 * 512];
    Sp0[lane]       = pack2h(a0x, a0y);
    Sp0[64 + lane]  = pack2h(a1x, a1y);
    Sp0[128 + lane] = pack2h(a2x, a2y);
    Sp0[192 + lane] = pack2h(a3x, a3y);
    if (has1) {
        unsigned int* Sp1 = (unsigned int*)&S[(size_t)v1 * 512];
        Sp1[lane]       = pack2h(a4x, a4y);
        Sp1[64 + lane]  = pack2h(a5x, a5y);
        Sp1[128 + lane] = pack2h(a6x, a6y);
        Sp1[192 + lane] = pack2h(a7x, a7y);
    }
}

// ---------- etype GEMM: C[64,128] tile, K=512, BK=64 as 2x32 panels, fp16 ----------
__global__ __launch_bounds__(256) void k_gemm0(
    const unsigned short* __restrict__ A, int M,
    const unsigned short* __restrict__ Bw,
    unsigned short* __restrict__ outAH, const int* __restrict__ cnt4,
    const float* __restrict__ b_et)
{
    __shared__ __align__(16) unsigned short As[2][64 * 32];
    __shared__ __align__(16) unsigned short Bs[2][128 * 32];
    const int tid  = threadIdx.x;
    const int lane = tid & 63;
    const int wv   = tid >> 6;
    const int wm   = (wv & 1) * 32;
    const int wn   = (wv >> 1) * 64;
    const int mBase = blockIdx.x * 64;
    const int srow = tid >> 2;          // 0..63
    const int sseg = (tid & 3) * 8;
    const int Ktot = 512;

    floatx4 acc[2][4];
#pragma unroll
    for (int i = 0; i < 2; ++i)
#pragma unroll
        for (int j = 0; j < 4; ++j) acc[i][j] = (floatx4){0.f, 0.f, 0.f, 0.f};

    int r0 = mBase + srow; if (r0 >= M) r0 = M - 1;

    for (int k0 = 0; k0 < Ktot; k0 += 64) {
        __syncthreads();
#pragma unroll
        for (int sub = 0; sub < 2; ++sub) {
            const int ko = k0 + sub * 32;
            load_lds16(A + (size_t)r0 * 512 + ko + sseg, &As[sub][srow * 32 + sseg]);
            const unsigned short* bw = Bw + (size_t)srow * Ktot + ko + sseg;
            load_lds16(bw,                     &Bs[sub][srow * 32 + sseg]);
            load_lds16(bw + (size_t)64 * Ktot, &Bs[sub][(srow + 64) * 32 + sseg]);
        }
        __syncthreads();
        const int kof = (lane >> 4) * 8;
        const int mr  = lane & 15;
#pragma unroll
        for (int p = 0; p < 2; ++p) {
            half8 af[2], bf[4];
#pragma unroll
            for (int i = 0; i < 2; ++i) af[i] = *(const half8*)&As[p][(wm + i * 16 + mr) * 32 + kof];
#pragma unroll
            for (int j = 0; j < 4; ++j) bf[j] = *(const half8*)&Bs[p][(wn + j * 16 + mr) * 32 + kof];
#pragma unroll
            for (int i = 0; i < 2; ++i)
#pragma unroll
                for (int j = 0; j < 4; ++j)
                    acc[i][j] = __builtin_amdgcn_mfma_f32_16x16x32_f16(af[i], bf[j], acc[i][j], 0, 0, 0);
        }
    }

    const int mr4 = (lane >> 4) * 4;
    const int nc  = lane & 15;
#pragma unroll
    for (int i = 0; i < 2; ++i) {
#pragma unroll
        for (int r = 0; r < 4; ++r) {
            int row = mBase + wm + i * 16 + mr4 + r;
            if (row < M) {
                int cx = cnt4[row * 4 + 0], cy = cnt4[row * 4 + 1];
                int cz = cnt4[row * 4 + 2], cw = cnt4[row * 4 + 3];
#pragma unroll
                for (int j = 0; j < 4; ++j) {
                    int col = wn + j * 16 + nc;
                    float val = acc[i][j][r]
                        + (float)cx * b_et[col]       + (float)cy * b_et[128 + col]
                        + (float)cz * b_et[256 + col] + (float)cw * b_et[384 + col];
                    outAH[(size_t)row * 256 + col] = f2hs(val);
                }
            }
        }
    }
}

// ---------- fused gates GEMM + GRU (retry of R1 fusion at BM=64) ----------
// R1 failed at 391 blocks / 200 VGPR / 8% occupancy (grid starvation). Here:
// 782 blocks (~3/CU), acc halved (BM=64), r/z/i_n packed to fp16 after their
// phase (~110 VGPR peak), LDS 40KB. Row-local: A rows = output rows = h rows,
// so no cross-block hazard. r,z,i_n carry the exact fp16 rounding the old G
// tensor had; h_n stays f32. Eliminates the 100 MB/step G round-trip + k_gru.
__global__ __launch_bounds__(256) void k_gates(
    unsigned short* AH, int M,
    const unsigned short* __restrict__ Wrz,
    const unsigned short* __restrict__ Win, const unsigned short* __restrict__ Whn,
    const float* __restrict__ b_ih, const float* __restrict__ b_hh)
{
    __shared__ __align__(16) unsigned short As[2][64 * 32];
    __shared__ __align__(16) unsigned short Bs[2][256 * 32];
    const int tid  = threadIdx.x;
    const int lane = tid & 63;
    const int wv   = tid >> 6;
    const int wm   = (wv & 1) * 32;
    const int wn   = (wv >> 1) * 64;
    const int mBase = blockIdx.x * 64;
    const int srow = tid >> 2;          // 0..63
    const int sseg = (tid & 3) * 8;
    const int kof  = (lane >> 4) * 8;
    const int mr   = lane & 15;

    int r0 = mBase + srow; if (r0 >= M) r0 = M - 1;

    // ---- phase 1: r and z jointly, K=256 over [a|h], B = Wrz rows 0..255 ----
    floatx4 acc_r[2][4], acc_z[2][4];
#pragma unroll
    for (int i = 0; i < 2; ++i)
#pragma unroll
        for (int j = 0; j < 4; ++j) {
            acc_r[i][j] = (floatx4){0.f, 0.f, 0.f, 0.f};
            acc_z[i][j] = (floatx4){0.f, 0.f, 0.f, 0.f};
        }

    for (int k0 = 0; k0 < 256; k0 += 64) {
        __syncthreads();
#pragma unroll
        for (int sub = 0; sub < 2; ++sub) {
            const int ko = k0 + sub * 32;
            load_lds16(AH + (size_t)r0 * 256 + ko + sseg, &As[sub][srow * 32 + sseg]);
            const unsigned short* b = Wrz + (size_t)srow * 256 + ko + sseg;
            load_lds16(b,                     &Bs[sub][srow * 32 + sseg]);
            load_lds16(b + (size_t)64 * 256,  &Bs[sub][(srow + 64) * 32 + sseg]);
            load_lds16(b + (size_t)128 * 256, &Bs[sub][(srow + 128) * 32 + sseg]);
            load_lds16(b + (size_t)192 * 256, &Bs[sub][(srow + 192) * 32 + sseg]);
        }
        __syncthreads();
#pragma unroll
        for (int p = 0; p < 2; ++p) {
            half8 af[2], br[4], bz[4];
#pragma unroll
            for (int i = 0; i < 2; ++i) af[i] = *(const half8*)&As[p][(wm + i * 16 + mr) * 32 + kof];
#pragma unroll
            for (int j = 0; j < 4; ++j) br[j] = *(const half8*)&Bs[p][(wn + j * 16 + mr) * 32 + kof];
#pragma unroll
            for (int j = 0; j < 4; ++j) bz[j] = *(const half8*)&Bs[p][(128 + wn + j * 16 + mr) * 32 + kof];
#pragma unroll
            for (int i = 0; i < 2; ++i)
#pragma unroll
                for (int j = 0; j < 4; ++j) {
                    acc_r[i][j] = __builtin_amdgcn_mfma_f32_16x16x32_f16(af[i], br[j], acc_r[i][j], 0, 0, 0);
                    acc_z[i][j] = __builtin_amdgcn_mfma_f32_16x16x32_f16(af[i], bz[j], acc_z[i][j], 0, 0, 0);
                }
        }
    }
    unsigned int r_pk[2][4][2], z_pk[2][4][2];
#pragma unroll
    for (int i = 0; i < 2; ++i)
#pragma unroll
        for (int j = 0; j < 4; ++j) {
            r_pk[i][j][0] = pack2h(acc_r[i][j][0], acc_r[i][j][1]);
            r_pk[i][j][1] = pack2h(acc_r[i][j][2], acc_r[i][j][3]);
            z_pk[i][j][0] = pack2h(acc_z[i][j][0], acc_z[i][j][1]);
            z_pk[i][j][1] = pack2h(acc_z[i][j][2], acc_z[i][j][3]);
        }

    // ---- phase 2: i_n, K=128 over a-half, B = Win ----
    floatx4 acc_n[2][4];
#pragma unroll
    for (int i = 0; i < 2; ++i)
#pragma unroll
        for (int j = 0; j < 4; ++j) acc_n[i][j] = (floatx4){0.f, 0.f, 0.f, 0.f};

    for (int k0 = 0; k0 < 128; k0 += 64) {
        __syncthreads();
#pragma unroll
        for (int sub = 0; sub < 2; ++sub) {
            const int ko = k0 + sub * 32;
            load_lds16(AH + (size_t)r0 * 256 + ko + sseg, &As[sub][srow * 32 + sseg]);
            const unsigned short* b = Win + (size_t)srow * 128 + ko + sseg;
            load_lds16(b,                    &Bs[sub][srow * 32 + sseg]);
            load_lds16(b + (size_t)64 * 128, &Bs[sub][(srow + 64) * 32 + sseg]);
        }
        __syncthreads();
#pragma unroll
        for (int p = 0; p < 2; ++p) {
            half8 af[2], bf[4];
#pragma unroll
            for (int i = 0; i < 2; ++i) af[i] = *(const half8*)&As[p][(wm + i * 16 + mr) * 32 + kof];
#pragma unroll
            for (int j = 0; j < 4; ++j) bf[j] = *(const half8*)&Bs[p][(wn + j * 16 + mr) * 32 + kof];
#pragma unroll
            for (int i = 0; i < 2; ++i)
#pragma unroll
                for (int j = 0; j < 4; ++j)
                    acc_n[i][j] = __builtin_amdgcn_mfma_f32_16x16x32_f16(af[i], bf[j], acc_n[i][j], 0, 0, 0);
        }
    }
    unsigned int n_pk[2][4][2];
#pragma unroll
    for (int i = 0; i < 2; ++i)
#pragma unroll
        for (int j = 0; j < 4; ++j) {
            n_pk[i][j][0] = pack2h(acc_n[i][j][0], acc_n[i][j][1]);
            n_pk[i][j][1] = pack2h(acc_n[i][j][2], acc_n[i][j][3]);
        }

    // ---- phase 3: h_n, K=128 over h-half, B = Whn (kept f32) ----
    floatx4 acc_h[2][4];
#pragma unroll
    for (int i = 0; i < 2; ++i)
#pragma unroll
        for (int j = 0; j < 4; ++j) acc_h[i][j] = (floatx4){0.f, 0.f, 0.f, 0.f};

    for (int k0 = 0; k0 < 128; k0 += 64) {
        __syncthreads();
#pragma unroll
        for (int sub = 0; sub < 2; ++sub) {
            const int ko = k0 + sub * 32;
            load_lds16(AH + (size_t)r0 * 256 + 128 + ko + sseg, &As[sub][srow * 32 + sseg]);
            const unsigned short* b = Whn + (size_t)srow * 128 + ko + sseg;
            load_lds16(b,                    &Bs[sub][srow * 32 + sseg]);
            load_lds16(b + (size_t)64 * 128, &Bs[sub][(srow + 64) * 32 + sseg]);
        }
        __syncthreads();
#pragma unroll
        for (int p = 0; p < 2; ++p) {
            half8 af[2], bf[4];
#pragma unroll
            for (int i = 0; i < 2; ++i) af[i] = *(const half8*)&As[p][(wm + i * 16 + mr) * 32 + kof];
#pragma unroll
            for (int j = 0; j < 4; ++j) bf[j] = *(const half8*)&Bs[p][(wn + j * 16 + mr) * 32 + kof];
#pragma unroll
            for (int i = 0; i < 2; ++i)
#pragma unroll
                for (int j = 0; j < 4; ++j)
                    acc_h[i][j] = __builtin_amdgcn_mfma_f32_16x16x32_f16(af[i], bf[j], acc_h[i][j], 0, 0, 0);
        }
    }

    // ---- GRU epilogue: h' = (1-z)*n + z*h, n = tanh(i_n + r*h_n) ----
    const int mr4 = (lane >> 4) * 4;
    const int nc  = lane & 15;
#pragma unroll
    for (int j = 0; j < 4; ++j) {
        const int col = wn + j * 16 + nc;                 // gate dim d in 0..127
        const float b_r  = b_ih[col]       + b_hh[col];
        const float b_z  = b_ih[128 + col] + b_hh[128 + col];
        const float b_in = b_ih[256 + col];
        const float b_hn = b_hh[256 + col];
#pragma unroll
        for (int i = 0; i < 2; ++i) {
#pragma unroll
            for (int r = 0; r < 4; ++r) {
                int row = mBase + wm + i * 16 + mr4 + r;
                if (row < M) {
                    H2 cr; cr.u = r_pk[i][j][r >> 1];
                    H2 cz; cz.u = z_pk[i][j][r >> 1];
                    H2 cn; cn.u = n_pk[i][j][r >> 1];
                    float rv = (float)cr.h[r & 1] + b_r;
                    float zv = (float)cz.h[r & 1] + b_z;
                    float iv = (float)cn.h[r & 1] + b_in;
                    float hv = acc_h[i][j][r] + b_hn;
                    rv = 1.f / (1.f + __expf(-rv));
                    zv = 1.f / (1.f + __expf(-zv));
                    float nv = tanhf(iv + rv * hv);
                    size_t off = (size_t)row * 256 + 128 + col;
                    float h = hs2f(AH[off]);
                    AH[off] = f2hs((1.f - zv) * nv + zv * h);
                }
            }
        }
    }
}

// ---------- readout stage 1: per-node classifier dot (no atomics) ----------
__global__ void k_dotv(const unsigned short* __restrict__ AH, const float* __restrict__ cls_w,
                       float* __restrict__ dotv, int N) {
    int v = blockIdx.x * 4 + (threadIdx.x >> 6);
    int lane = threadIdx.x & 63;
    if (v >= N) return;
    H2 c; c.u = *(const unsigned int*)&AH[(size_t)v * 256 + 128 + lane * 2];
    float x = (float)c.h[0] * cls_w[lane * 2]
            + (float)c.h[1] * cls_w[lane * 2 + 1];
#pragma unroll
    for (int off = 32; off > 0; off >>= 1) x += __shfl_down(x, off);
    if (lane == 0) dotv[v] = x;
}

// ---------- readout stage 2: per-graph sum over sorted gids + sigmoid ----------
__global__ void k_gsum(const float* __restrict__ dotv, const int* __restrict__ gids,
                       const float* __restrict__ cls_b, float* __restrict__ out, int N) {
    int g = blockIdx.x;
    int t = threadIdx.x;   // 256
    int lo = 0, hi = N;
    while (lo < hi) { int m = (lo + hi) >> 1; if (gids[m] < g) lo = m + 1; else hi = m; }
    int s = lo;
    lo = 0; hi = N;
    while (lo < hi) { int m = (lo + hi) >> 1; if (gids[m] < g + 1) lo = m + 1; else hi = m; }
    int e = lo;
    float acc = 0.f;
    for (int v = s + t; v < e; v += 256) acc += dotv[v];
    __shared__ float red[256];
    red[t] = acc;
    __syncthreads();
    for (int off = 128; off > 0; off >>= 1) {
        if (t < off) red[t] += red[t + off];
        __syncthreads();
    }
    if (t == 0) out[g] = 1.f / (1.f + expf(-(red[0] + cls_b[0])));
}

// ---------- host ----------
extern "C" void kernel_launch(void* const* d_in, const int* in_sizes, int n_in,
                              void* d_out, int out_size, void* d_ws, size_t ws_size,
                              hipStream_t stream) {
    const float* features = (const float*)d_in[0];
    const int*   src      = (const int*)d_in[1];
    const int*   dst      = (const int*)d_in[2];
    const int*   etype    = (const int*)d_in[3];
    const int*   gids     = (const int*)d_in[4];
    const float* W_etype  = (const float*)d_in[5];
    const float* b_etype  = (const float*)d_in[6];
    const float* W_ih     = (const float*)d_in[7];
    const float* W_hh     = (const float*)d_in[8];
    const float* b_ih     = (const float*)d_in[9];
    const float* b_hh     = (const float*)d_in[10];
    const float* cls_w    = (const float*)d_in[11];
    const float* cls_b    = (const float*)d_in[12];
    const int N = in_sizes[0] / 128;
    const int E = in_sizes[1];
    float* out = (float*)d_out;

    char* ws = (char*)d_ws;
    size_t off = 0;
    auto alloc = [&](size_t bytes) -> void* {
        off = (off + 255) & ~(size_t)255;
        void* p = ws + off;
        off += bytes;
        return p;
    };
    unsigned short* AH  = (unsigned short*)alloc((size_t)N * 256 * 2); // [a | h] fp16
    unsigned short* S   = (unsigned short*)alloc((size_t)N * 512 * 2); // fp16
    unsigned short* Wc  = (unsigned short*)alloc(128 * 512 * 2);
    unsigned short* Wrz = (unsigned short*)alloc(256 * 256 * 2);
    unsigned short* Win = (unsigned short*)alloc(128 * 128 * 2);
    unsigned short* Whn = (unsigned short*)alloc(128 * 128 * 2);
    int* row_ptr = (int*)alloc((size_t)(N + 1) * 4);
    int* cursor4 = (int*)alloc((size_t)N * 16);
    int* cnt4    = (int*)alloc((size_t)N * 16);
    int* edge_pk = (int*)alloc((size_t)E * 4);
    float* dotv  = (float*)alloc((size_t)N * 4);
    int* bsum    = (int*)alloc(256 * 4);
    int* boff    = (int*)alloc(256 * 4);
    (void)ws_size; (void)n_in;

    const int nscan = (N + 255) / 256;   // must be <= 256
    hipMemsetAsync(cnt4, 0, (size_t)N * 16, stream);
    k_hist<<<(E + 255) / 256, 256, 0, stream>>>(dst, etype, cnt4, E);
    k_scan_blk<<<nscan, 256, 0, stream>>>(cnt4, row_ptr, bsum, N);
    k_scan_top<<<1, 256, 0, stream>>>(bsum, boff, row_ptr, nscan, N);
    k_scan_add<<<nscan, 256, 0, stream>>>(row_ptr, cursor4, boff, cnt4, N);
    k_scatter<<<(E + 255) / 256, 256, 0, stream>>>(src, dst, etype, cursor4, edge_pk, E);
    k_init_h<<<(N * 128 + 255) / 256, 256, 0, stream>>>(features, AH, N);
    k_prep_wcat<<<65536 / 256, 256, 0, stream>>>(W_etype, Wc);
    k_prep_wrz<<<(256 * 256) / 256, 256, 0, stream>>>(W_ih, W_hh, Wrz);
    k_prep_wnh<<<(128 * 128) / 256, 256, 0, stream>>>(W_ih, W_hh, Win, Whn);

    const int mblocks64 = (N + 63) / 64;
    for (int s = 0; s < 8; ++s) {
        k_aggregate<<<(N + 7) / 8, 256, 0, stream>>>(row_ptr, cnt4, edge_pk, AH, S, N);
        k_gemm0<<<mblocks64, 256, 0, stream>>>(S, N, Wc, AH, cnt4, b_etype);
        k_gates<<<mblocks64, 256, 0, stream>>>(AH, N, Wrz, Win, Whn, b_ih, b_hh);
    }
    k_dotv<<<(N + 3) / 4, 256, 0, stream>>>(AH, cls_w, dotv, N);
    k_gsum<<<out_size, 256, 0, stream>>>(dotv, gids, cls_b, out, N);
}

// Round 8
// 1071.710 us; speedup vs baseline: 1.1581x; 1.1581x over previous
//
#include <hip/hip_runtime.h>

typedef __attribute__((ext_vector_type(4))) float floatx4;
typedef __attribute__((ext_vector_type(8))) _Float16 half8;

// ---------- fp16 helpers (RNE via _Float16 convert) ----------
union H2 { unsigned int u; _Float16 h[2]; };

__device__ __forceinline__ float hs2f(unsigned short u) {
    union { unsigned short u; _Float16 h; } c; c.u = u; return (float)c.h;
}
__device__ __forceinline__ unsigned short f2hs(float f) {
    union { unsigned short u; _Float16 h; } c; c.h = (_Float16)f; return c.u;
}
__device__ __forceinline__ unsigned int pack2h(float a, float b) {
    H2 c; c.h[0] = (_Float16)a; c.h[1] = (_Float16)b; return c.u;
}

// ---------- async global->LDS, 16B per lane ----------
__device__ __forceinline__ void load_lds16(const unsigned short* g, unsigned short* l) {
    __builtin_amdgcn_global_load_lds(
        (__attribute__((address_space(1))) void*)(g),
        (__attribute__((address_space(3))) void*)(l), 16, 0, 0);
}

// ---------- CSR build ----------
__global__ void k_hist(const int* __restrict__ dst, const int* __restrict__ et,
                       int* __restrict__ cnt4, int E) {
    int i = blockIdx.x * 256 + threadIdx.x;
    if (i < E) {
        atomicAdd(&cnt4[dst[i] * 4 + et[i]], 1);
    }
}

__global__ void k_scan_blk(const int* __restrict__ cnt4, int* __restrict__ row_ptr,
                           int* __restrict__ bsum, int N) {
    __shared__ int sm[256];
    int b = blockIdx.x, t = threadIdx.x, i = b * 256 + t;
    int v = 0;
    if (i < N) {
        const int4 q = ((const int4*)cnt4)[i];
        v = q.x + q.y + q.z + q.w;
    }
    sm[t] = v;
    __syncthreads();
    for (int off = 1; off < 256; off <<= 1) {
        int x = (t >= off) ? sm[t - off] : 0;
        __syncthreads();
        sm[t] += x;
        __syncthreads();
    }
    if (i < N) row_ptr[i] = sm[t] - v;
    if (t == 255) bsum[b] = sm[255];
}

__global__ void k_scan_top(int* __restrict__ bsum, int* __restrict__ boff,
                           int* __restrict__ row_ptr, int nblocks, int N) {
    __shared__ int sm[256];
    int t = threadIdx.x;
    int v = (t < nblocks) ? bsum[t] : 0;
    sm[t] = v;
    __syncthreads();
    for (int off = 1; off < 256; off <<= 1) {
        int x = (t >= off) ? sm[t - off] : 0;
        __syncthreads();
        sm[t] += x;
        __syncthreads();
    }
    if (t < nblocks) boff[t] = sm[t] - v;
    if (t == 255) row_ptr[N] = sm[255];
}

// per-(dst,type) segment cursors: cursor4[v][t] = row_ptr[v] + prefix(cnt4[v][0..t-1])
__global__ void k_scan_add(int* __restrict__ row_ptr, int* __restrict__ cursor4,
                           const int* __restrict__ boff, const int* __restrict__ cnt4, int N) {
    int i = blockIdx.x * 256 + threadIdx.x;
    if (i < N) {
        int r = row_ptr[i] + boff[blockIdx.x];
        row_ptr[i] = r;
        const int4 q = ((const int4*)cnt4)[i];
        int4 c;
        c.x = r;
        c.y = r + q.x;
        c.z = r + q.x + q.y;
        c.w = r + q.x + q.y + q.z;
        ((int4*)cursor4)[i] = c;
    }
}

// edges sorted by (dst, etype): segment pick in aggregate is wave-uniform scalar.
__global__ void k_scatter(const int* __restrict__ src, const int* __restrict__ dst,
                          const int* __restrict__ et, int* __restrict__ cursor4,
                          int* __restrict__ edge_pk, int E) {
    int i = blockIdx.x * 256 + threadIdx.x;
    if (i < E) {
        int p = atomicAdd(&cursor4[dst[i] * 4 + et[i]], 1);
        edge_pk[p] = src[i];
    }
}

// ---------- init h (fp16) into AH[:,128:256] ----------
__global__ void k_init_h(const float* __restrict__ feat, unsigned short* __restrict__ AH, int N) {
    int i = blockIdx.x * 256 + threadIdx.x;
    if (i < N * 128) {
        int v = i >> 7, d = i & 127;
        AH[(size_t)v * 256 + 128 + d] = f2hs(feat[i]);
    }
}

// ---------- weight prep: single fp16, n-major [Nout][K] ----------
__global__ void k_prep_wcat(const float* __restrict__ W, unsigned short* __restrict__ w) {
    int i = blockIdx.x * 256 + threadIdx.x;   // 4*128*128 = 65536
    if (i < 65536) {
        int t = i >> 14, o = (i >> 7) & 127, d = i & 127;
        w[o * 512 + t * 128 + d] = f2hs(W[i]);
    }
}

// r,z rows: Wrz[256][256], row j = [W_ih[j] | W_hh[j]]
__global__ void k_prep_wrz(const float* __restrict__ Wih, const float* __restrict__ Whh,
                           unsigned short* __restrict__ w) {
    int i = blockIdx.x * 256 + threadIdx.x;   // 256*256
    if (i < 256 * 256) {
        int j = i >> 8, k = i & 255;
        float v = (k < 128) ? Wih[j * 128 + k] : Whh[j * 128 + (k - 128)];
        w[i] = f2hs(v);
    }
}

// i_n rows: Win[128][128] = W_ih rows 256..383 ; h_n rows: Whn[128][128] = W_hh rows 256..383
__global__ void k_prep_wnh(const float* __restrict__ Wih, const float* __restrict__ Whh,
                           unsigned short* __restrict__ win, unsigned short* __restrict__ whn) {
    int i = blockIdx.x * 256 + threadIdx.x;   // 128*128
    if (i < 128 * 128) {
        int c = i >> 7, k = i & 127;
        win[i] = f2hs(Wih[(256 + c) * 128 + k]);
        whn[i] = f2hs(Whh[(256 + c) * 128 + k]);
    }
}

// ---------- per-step: aggregate h[src] by (dst, etype): S[v][t*128+d] ----------
// 2 nodes/wave, 12-deep batches, now SOFTWARE-PIPELINED 2 deep: while batch k
// accumulates (gathers issued in iter k-1), batch k+1's gathers are issued and
// batch k+2's edge_pk loads are in flight. Breaks the serial edge_pk->gather->
// accumulate latency chain (measured 3.2 TB/s HBM over 33us = latency-bound,
// not BW-bound). Guards are wave-uniform scalar. Per-(lane,node,type)
// accumulation order = edge order (bit-identical numerics).
__global__ __launch_bounds__(256) void k_aggregate(
    const int* __restrict__ row_ptr, const int* __restrict__ cnt4,
    const int* __restrict__ edge_pk,
    const unsigned short* __restrict__ AH, unsigned short* __restrict__ S, int N)
{
    const int wv = threadIdx.x >> 6;
    const int lane = threadIdx.x & 63;
    const int v0 = blockIdx.x * 8 + wv * 2;
    if (v0 >= N) return;
    const int v1 = v0 + 1;
    const bool has1 = (v1 < N);

    const int beg0 = __builtin_amdgcn_readfirstlane(row_ptr[v0]);
    const int end0 = __builtin_amdgcn_readfirstlane(row_ptr[v0 + 1]);
    const int end1 = has1 ? __builtin_amdgcn_readfirstlane(row_ptr[v1 + 1]) : end0;
    const int4 q0 = ((const int4*)cnt4)[v0];
    const int c1 = beg0 + __builtin_amdgcn_readfirstlane(q0.x);
    const int c2 = c1 + __builtin_amdgcn_readfirstlane(q0.y);
    const int c3 = c2 + __builtin_amdgcn_readfirstlane(q0.z);
    const int c4 = end0;
    int c5 = end0, c6 = end0, c7 = end0;
    if (has1) {
        const int4 q1 = ((const int4*)cnt4)[v1];
        c5 = end0 + __builtin_amdgcn_readfirstlane(q1.x);
        c6 = c5 + __builtin_amdgcn_readfirstlane(q1.y);
        c7 = c6 + __builtin_amdgcn_readfirstlane(q1.z);
    }

    float a0x=0,a0y=0,a1x=0,a1y=0,a2x=0,a2y=0,a3x=0,a3y=0;
    float a4x=0,a4y=0,a5x=0,a5y=0,a6x=0,a6y=0,a7x=0,a7y=0;
    const unsigned short* hbase = AH + 128 + lane * 2;

#define CLAMPE(i) ((i) > end1 - 1 ? end1 - 1 : (i))
#define ACCUM(IDX, HV)                                                        \
    {                                                                         \
        H2 c_; c_.u = (HV);                                                   \
        float x0 = (float)c_.h[0];                                            \
        float x1 = (float)c_.h[1];                                            \
        if ((IDX) < c4) {                                                     \
            if ((IDX) < c2) { if ((IDX) < c1) { a0x+=x0; a0y+=x1; } else { a1x+=x0; a1y+=x1; } } \
            else            { if ((IDX) < c3) { a2x+=x0; a2y+=x1; } else { a3x+=x0; a3y+=x1; } } \
        } else {                                                              \
            if ((IDX) < c6) { if ((IDX) < c5) { a4x+=x0; a4y+=x1; } else { a5x+=x0; a5y+=x1; } } \
            else            { if ((IDX) < c7) { a6x+=x0; a6y+=x1; } else { a7x+=x0; a7y+=x1; } } \
        }                                                                     \
    }

    if (beg0 < end1) {
        int sp0[12], sp1[12];
        unsigned int hv0[12], hv1[12];
        // prologue: ep + gathers for batch 0; ep for batch 1
#pragma unroll
        for (int u = 0; u < 12; ++u) sp0[u] = edge_pk[CLAMPE(beg0 + u)];
#pragma unroll
        for (int u = 0; u < 12; ++u)
            hv0[u] = *(const unsigned int*)(hbase + (size_t)sp0[u] * 256);
#pragma unroll
        for (int u = 0; u < 12; ++u) sp1[u] = edge_pk[CLAMPE(beg0 + 12 + u)];

        for (int e = beg0; e < end1; e += 24) {
            // ---- half A: consume batch e (hv0), feed pipeline ----
            if (e + 12 < end1) {
#pragma unroll
                for (int u = 0; u < 12; ++u)
                    hv1[u] = *(const unsigned int*)(hbase + (size_t)sp1[u] * 256);
            }
            if (e + 24 < end1) {
#pragma unroll
                for (int u = 0; u < 12; ++u) sp0[u] = edge_pk[CLAMPE(e + 24 + u)];
            }
#pragma unroll
            for (int u = 0; u < 12; ++u) {
                const int idx = e + u;                  // wave-uniform
                if (idx < end1) ACCUM(idx, hv0[u]);
            }
            // ---- half B: consume batch e+12 (hv1), feed pipeline ----
            if (e + 12 < end1) {
                if (e + 24 < end1) {
#pragma unroll
                    for (int u = 0; u < 12; ++u)
                        hv0[u] = *(const unsigned int*)(hbase + (size_t)sp0[u] * 256);
                }
                if (e + 36 < end1) {
#pragma unroll
                    for (int u = 0; u < 12; ++u) sp1[u] = edge_pk[CLAMPE(e + 36 + u)];
                }
#pragma unroll
                for (int u = 0; u < 12; ++u) {
                    const int idx = e + 12 + u;         // wave-uniform
                    if (idx < end1) ACCUM(idx, hv1[u]);
                }
            }
        }
    }
#undef ACCUM
#undef CLAMPE

    unsigned int* Sp0 = (unsigned int*)&S[(size_t)v0 * 512];
    Sp0[lane]       = pack2h(a0x, a0y);
    Sp0[64 + lane]  = pack2h(a1x, a1y);
    Sp0[128 + lane] = pack2h(a2x, a2y);
    Sp0[192 + lane] = pack2h(a3x, a3y);
    if (has1) {
        unsigned int* Sp1 = (unsigned int*)&S[(size_t)v1 * 512];
        Sp1[lane]       = pack2h(a4x, a4y);
        Sp1[64 + lane]  = pack2h(a5x, a5y);
        Sp1[128 + lane] = pack2h(a6x, a6y);
        Sp1[192 + lane] = pack2h(a7x, a7y);
    }
}

// ---------- etype GEMM: C[64,128] tile, K=512, BK=64 as 2x32 panels, fp16 ----------
__global__ __launch_bounds__(256) void k_gemm0(
    const unsigned short* __restrict__ A, int M,
    const unsigned short* __restrict__ Bw,
    unsigned short* __restrict__ outAH, const int* __restrict__ cnt4,
    const float* __restrict__ b_et)
{
    __shared__ __align__(16) unsigned short As[2][64 * 32];
    __shared__ __align__(16) unsigned short Bs[2][128 * 32];
    const int tid  = threadIdx.x;
    const int lane = tid & 63;
    const int wv   = tid >> 6;
    const int wm   = (wv & 1) * 32;
    const int wn   = (wv >> 1) * 64;
    const int mBase = blockIdx.x * 64;
    const int srow = tid >> 2;          // 0..63
    const int sseg = (tid & 3) * 8;
    const int Ktot = 512;

    floatx4 acc[2][4];
#pragma unroll
    for (int i = 0; i < 2; ++i)
#pragma unroll
        for (int j = 0; j < 4; ++j) acc[i][j] = (floatx4){0.f, 0.f, 0.f, 0.f};

    int r0 = mBase + srow; if (r0 >= M) r0 = M - 1;

    for (int k0 = 0; k0 < Ktot; k0 += 64) {
        __syncthreads();
#pragma unroll
        for (int sub = 0; sub < 2; ++sub) {
            const int ko = k0 + sub * 32;
            load_lds16(A + (size_t)r0 * 512 + ko + sseg, &As[sub][srow * 32 + sseg]);
            const unsigned short* bw = Bw + (size_t)srow * Ktot + ko + sseg;
            load_lds16(bw,                     &Bs[sub][srow * 32 + sseg]);
            load_lds16(bw + (size_t)64 * Ktot, &Bs[sub][(srow + 64) * 32 + sseg]);
        }
        __syncthreads();
        const int kof = (lane >> 4) * 8;
        const int mr  = lane & 15;
#pragma unroll
        for (int p = 0; p < 2; ++p) {
            half8 af[2], bf[4];
#pragma unroll
            for (int i = 0; i < 2; ++i) af[i] = *(const half8*)&As[p][(wm + i * 16 + mr) * 32 + kof];
#pragma unroll
            for (int j = 0; j < 4; ++j) bf[j] = *(const half8*)&Bs[p][(wn + j * 16 + mr) * 32 + kof];
#pragma unroll
            for (int i = 0; i < 2; ++i)
#pragma unroll
                for (int j = 0; j < 4; ++j)
                    acc[i][j] = __builtin_amdgcn_mfma_f32_16x16x32_f16(af[i], bf[j], acc[i][j], 0, 0, 0);
        }
    }

    const int mr4 = (lane >> 4) * 4;
    const int nc  = lane & 15;
#pragma unroll
    for (int i = 0; i < 2; ++i) {
#pragma unroll
        for (int r = 0; r < 4; ++r) {
            int row = mBase + wm + i * 16 + mr4 + r;
            if (row < M) {
                int cx = cnt4[row * 4 + 0], cy = cnt4[row * 4 + 1];
                int cz = cnt4[row * 4 + 2], cw = cnt4[row * 4 + 3];
#pragma unroll
                for (int j = 0; j < 4; ++j) {
                    int col = wn + j * 16 + nc;
                    float val = acc[i][j][r]
                        + (float)cx * b_et[col]       + (float)cy * b_et[128 + col]
                        + (float)cz * b_et[256 + col] + (float)cw * b_et[384 + col];
                    outAH[(size_t)row * 256 + col] = f2hs(val);
                }
            }
        }
    }
}

// ---------- gates GEMM, zero-block-eliminated K-split, fp16, BM=64 ----------
// grid (mblocks64, 4): y=0,1 -> r,z cols (K=256); y=2 -> i_n (K=128, a-half);
// y=3 -> h_n (K=128, h-half). Fused gates+GRU kernel measured 80+us at 8%
// occupancy TWICE (R1 @ BM=128, R7 @ BM=64) -- split is structurally better:
// the 4 independent y-families overlap each other's barrier drains.
__global__ __launch_bounds__(256) void k_gemm1(
    const unsigned short* __restrict__ A, int M,
    const unsigned short* __restrict__ Wrz,
    const unsigned short* __restrict__ Win, const unsigned short* __restrict__ Whn,
    _Float16* __restrict__ G)
{
    __shared__ __align__(16) unsigned short As[2][64 * 32];
    __shared__ __align__(16) unsigned short Bs[2][128 * 32];
    const int tid  = threadIdx.x;
    const int lane = tid & 63;
    const int wv   = tid >> 6;
    const int wm   = (wv & 1) * 32;
    const int wn   = (wv >> 1) * 64;
    const int mBase = blockIdx.x * 64;
    const int y    = blockIdx.y;
    const int srow = tid >> 2;          // 0..63
    const int sseg = (tid & 3) * 8;

    const unsigned short* Bw;
    int Ktot, aOff, colBase;
    if (y < 2)      { Bw = Wrz + (size_t)y * 128 * 256; Ktot = 256; aOff = 0;   colBase = y * 128; }
    else if (y == 2){ Bw = Win; Ktot = 128; aOff = 0;   colBase = 256; }
    else            { Bw = Whn; Ktot = 128; aOff = 128; colBase = 384; }

    floatx4 acc[2][4];
#pragma unroll
    for (int i = 0; i < 2; ++i)
#pragma unroll
        for (int j = 0; j < 4; ++j) acc[i][j] = (floatx4){0.f, 0.f, 0.f, 0.f};

    int r0 = mBase + srow; if (r0 >= M) r0 = M - 1;

    for (int k0 = 0; k0 < Ktot; k0 += 64) {
        __syncthreads();
#pragma unroll
        for (int sub = 0; sub < 2; ++sub) {
            const int ko = k0 + sub * 32;
            load_lds16(A + (size_t)r0 * 256 + aOff + ko + sseg, &As[sub][srow * 32 + sseg]);
            const unsigned short* bw = Bw + (size_t)srow * Ktot + ko + sseg;
            load_lds16(bw,                     &Bs[sub][srow * 32 + sseg]);
            load_lds16(bw + (size_t)64 * Ktot, &Bs[sub][(srow + 64) * 32 + sseg]);
        }
        __syncthreads();
        const int kof = (lane >> 4) * 8;
        const int mr  = lane & 15;
#pragma unroll
        for (int p = 0; p < 2; ++p) {
            half8 af[2], bf[4];
#pragma unroll
            for (int i = 0; i < 2; ++i) af[i] = *(const half8*)&As[p][(wm + i * 16 + mr) * 32 + kof];
#pragma unroll
            for (int j = 0; j < 4; ++j) bf[j] = *(const half8*)&Bs[p][(wn + j * 16 + mr) * 32 + kof];
#pragma unroll
            for (int i = 0; i < 2; ++i)
#pragma unroll
                for (int j = 0; j < 4; ++j)
                    acc[i][j] = __builtin_amdgcn_mfma_f32_16x16x32_f16(af[i], bf[j], acc[i][j], 0, 0, 0);
        }
    }

    const int mr4 = (lane >> 4) * 4;
    const int nc  = lane & 15;
#pragma unroll
    for (int i = 0; i < 2; ++i) {
#pragma unroll
        for (int r = 0; r < 4; ++r) {
            int row = mBase + wm + i * 16 + mr4 + r;
            if (row < M) {
#pragma unroll
                for (int j = 0; j < 4; ++j) {
                    int col = colBase + wn + j * 16 + nc;
                    G[(size_t)row * 512 + col] = (_Float16)acc[i][j][r];
                }
            }
        }
    }
}

// ---------- GRU elementwise (fp16 G, 2 dims/thread) ----------
__global__ void k_gru(const _Float16* __restrict__ G, unsigned short* __restrict__ AH,
                      const float* __restrict__ b_ih, const float* __restrict__ b_hh, int N) {
    int i = blockIdx.x * 256 + threadIdx.x;
    if (i >= N * 64) return;
    int v = i >> 6, j = i & 63;          // pair index (2 dims)
    const unsigned int* g32 = (const unsigned int*)(G + (size_t)v * 512);
    H2 pr, pz, pn, ph;
    pr.u = g32[j];
    pz.u = g32[64 + j];
    pn.u = g32[128 + j];
    ph.u = g32[192 + j];
    H2 hv; hv.u = *(const unsigned int*)&AH[(size_t)v * 256 + 128 + j * 2];
    float outs[2];
#pragma unroll
    for (int q = 0; q < 2; ++q) {
        int d = j * 2 + q;
        float pre_r = (float)pr.h[q] + b_ih[d]       + b_hh[d];
        float pre_z = (float)pz.h[q] + b_ih[128 + d] + b_hh[128 + d];
        float i_n   = (float)pn.h[q] + b_ih[256 + d];
        float h_n   = (float)ph.h[q] + b_hh[256 + d];
        float r = 1.f / (1.f + __expf(-pre_r));
        float z = 1.f / (1.f + __expf(-pre_z));
        float n = tanhf(i_n + r * h_n);
        float h = (float)hv.h[q];
        outs[q] = (1.f - z) * n + z * h;
    }
    *(unsigned int*)&AH[(size_t)v * 256 + 128 + j * 2] = pack2h(outs[0], outs[1]);
}

// ---------- readout stage 1: per-node classifier dot (no atomics) ----------
__global__ void k_dotv(const unsigned short* __restrict__ AH, const float* __restrict__ cls_w,
                       float* __restrict__ dotv, int N) {
    int v = blockIdx.x * 4 + (threadIdx.x >> 6);
    int lane = threadIdx.x & 63;
    if (v >= N) return;
    H2 c; c.u = *(const unsigned int*)&AH[(size_t)v * 256 + 128 + lane * 2];
    float x = (float)c.h[0] * cls_w[lane * 2]
            + (float)c.h[1] * cls_w[lane * 2 + 1];
#pragma unroll
    for (int off = 32; off > 0; off >>= 1) x += __shfl_down(x, off);
    if (lane == 0) dotv[v] = x;
}

// ---------- readout stage 2: per-graph sum over sorted gids + sigmoid ----------
__global__ void k_gsum(const float* __restrict__ dotv, const int* __restrict__ gids,
                       const float* __restrict__ cls_b, float* __restrict__ out, int N) {
    int g = blockIdx.x;
    int t = threadIdx.x;   // 256
    int lo = 0, hi = N;
    while (lo < hi) { int m = (lo + hi) >> 1; if (gids[m] < g) lo = m + 1; else hi = m; }
    int s = lo;
    lo = 0; hi = N;
    while (lo < hi) { int m = (lo + hi) >> 1; if (gids[m] < g + 1) lo = m + 1; else hi = m; }
    int e = lo;
    float acc = 0.f;
    for (int v = s + t; v < e; v += 256) acc += dotv[v];
    __shared__ float red[256];
    red[t] = acc;
    __syncthreads();
    for (int off = 128; off > 0; off >>= 1) {
        if (t < off) red[t] += red[t + off];
        __syncthreads();
    }
    if (t == 0) out[g] = 1.f / (1.f + expf(-(red[0] + cls_b[0])));
}

// ---------- host ----------
extern "C" void kernel_launch(void* const* d_in, const int* in_sizes, int n_in,
                              void* d_out, int out_size, void* d_ws, size_t ws_size,
                              hipStream_t stream) {
    const float* features = (const float*)d_in[0];
    const int*   src      = (const int*)d_in[1];
    const int*   dst      = (const int*)d_in[2];
    const int*   etype    = (const int*)d_in[3];
    const int*   gids     = (const int*)d_in[4];
    const float* W_etype  = (const float*)d_in[5];
    const float* b_etype  = (const float*)d_in[6];
    const float* W_ih     = (const float*)d_in[7];
    const float* W_hh     = (const float*)d_in[8];
    const float* b_ih     = (const float*)d_in[9];
    const float* b_hh     = (const float*)d_in[10];
    const float* cls_w    = (const float*)d_in[11];
    const float* cls_b    = (const float*)d_in[12];
    const int N = in_sizes[0] / 128;
    const int E = in_sizes[1];
    float* out = (float*)d_out;

    char* ws = (char*)d_ws;
    size_t off = 0;
    auto alloc = [&](size_t bytes) -> void* {
        off = (off + 255) & ~(size_t)255;
        void* p = ws + off;
        off += bytes;
        return p;
    };
    unsigned short* AH  = (unsigned short*)alloc((size_t)N * 256 * 2); // [a | h] fp16
    unsigned short* S   = (unsigned short*)alloc((size_t)N * 512 * 2); // fp16
    _Float16*       G   = (_Float16*)alloc((size_t)N * 512 * 2);       // fp16 gates
    unsigned short* Wc  = (unsigned short*)alloc(128 * 512 * 2);
    unsigned short* Wrz = (unsigned short*)alloc(256 * 256 * 2);
    unsigned short* Win = (unsigned short*)alloc(128 * 128 * 2);
    unsigned short* Whn = (unsigned short*)alloc(128 * 128 * 2);
    int* row_ptr = (int*)alloc((size_t)(N + 1) * 4);
    int* cursor4 = (int*)alloc((size_t)N * 16);
    int* cnt4    = (int*)alloc((size_t)N * 16);
    int* edge_pk = (int*)alloc((size_t)E * 4);
    float* dotv  = (float*)alloc((size_t)N * 4);
    int* bsum    = (int*)alloc(256 * 4);
    int* boff    = (int*)alloc(256 * 4);
    (void)ws_size; (void)n_in;

    const int nscan = (N + 255) / 256;   // must be <= 256
    hipMemsetAsync(cnt4, 0, (size_t)N * 16, stream);
    k_hist<<<(E + 255) / 256, 256, 0, stream>>>(dst, etype, cnt4, E);
    k_scan_blk<<<nscan, 256, 0, stream>>>(cnt4, row_ptr, bsum, N);
    k_scan_top<<<1, 256, 0, stream>>>(bsum, boff, row_ptr, nscan, N);
    k_scan_add<<<nscan, 256, 0, stream>>>(row_ptr, cursor4, boff, cnt4, N);
    k_scatter<<<(E + 255) / 256, 256, 0, stream>>>(src, dst, etype, cursor4, edge_pk, E);
    k_init_h<<<(N * 128 + 255) / 256, 256, 0, stream>>>(features, AH, N);
    k_prep_wcat<<<65536 / 256, 256, 0, stream>>>(W_etype, Wc);
    k_prep_wrz<<<(256 * 256) / 256, 256, 0, stream>>>(W_ih, W_hh, Wrz);
    k_prep_wnh<<<(128 * 128) / 256, 256, 0, stream>>>(W_ih, W_hh, Win, Whn);

    const int mblocks64 = (N + 63) / 64;
    for (int s = 0; s < 8; ++s) {
        k_aggregate<<<(N + 7) / 8, 256, 0, stream>>>(row_ptr, cnt4, edge_pk, AH, S, N);
        k_gemm0<<<mblocks64, 256, 0, stream>>>(S, N, Wc, AH, cnt4, b_etype);
        dim3 g2(mblocks64, 4);
        k_gemm1<<<g2, 256, 0, stream>>>(AH, N, Wrz, Win, Whn, G);
        k_gru<<<(N * 64 + 255) / 256, 256, 0, stream>>>(G, AH, b_ih, b_hh, N);
    }
    k_dotv<<<(N + 3) / 4, 256, 0, stream>>>(AH, cls_w, dotv, N);
    k_gsum<<<out_size, 256, 0, stream>>>(dotv, gids, cls_b, out, N);
}

// Round 9
// 961.230 us; speedup vs baseline: 1.2913x; 1.1149x over previous
//
#include <hip/hip_runtime.h>

typedef __attribute__((ext_vector_type(4))) float floatx4;
typedef __attribute__((ext_vector_type(8))) _Float16 half8;

// ---------- fp16 helpers (RNE via _Float16 convert) ----------
union H2 { unsigned int u; _Float16 h[2]; };

__device__ __forceinline__ float hs2f(unsigned short u) {
    union { unsigned short u; _Float16 h; } c; c.u = u; return (float)c.h;
}
__device__ __forceinline__ unsigned short f2hs(float f) {
    union { unsigned short u; _Float16 h; } c; c.h = (_Float16)f; return c.u;
}
__device__ __forceinline__ unsigned int pack2h(float a, float b) {
    H2 c; c.h[0] = (_Float16)a; c.h[1] = (_Float16)b; return c.u;
}

// ---------- async global->LDS, 16B per lane ----------
__device__ __forceinline__ void load_lds16(const unsigned short* g, unsigned short* l) {
    __builtin_amdgcn_global_load_lds(
        (__attribute__((address_space(1))) void*)(g),
        (__attribute__((address_space(3))) void*)(l), 16, 0, 0);
}

// ---------- CSR build ----------
__global__ void k_hist(const int* __restrict__ dst, const int* __restrict__ et,
                       int* __restrict__ cnt4, int E) {
    int i = blockIdx.x * 256 + threadIdx.x;
    if (i < E) {
        atomicAdd(&cnt4[dst[i] * 4 + et[i]], 1);
    }
}

__global__ void k_scan_blk(const int* __restrict__ cnt4, int* __restrict__ row_ptr,
                           int* __restrict__ bsum, int N) {
    __shared__ int sm[256];
    int b = blockIdx.x, t = threadIdx.x, i = b * 256 + t;
    int v = 0;
    if (i < N) {
        const int4 q = ((const int4*)cnt4)[i];
        v = q.x + q.y + q.z + q.w;
    }
    sm[t] = v;
    __syncthreads();
    for (int off = 1; off < 256; off <<= 1) {
        int x = (t >= off) ? sm[t - off] : 0;
        __syncthreads();
        sm[t] += x;
        __syncthreads();
    }
    if (i < N) row_ptr[i] = sm[t] - v;
    if (t == 255) bsum[b] = sm[255];
}

__global__ void k_scan_top(int* __restrict__ bsum, int* __restrict__ boff,
                           int* __restrict__ row_ptr, int nblocks, int N) {
    __shared__ int sm[256];
    int t = threadIdx.x;
    int v = (t < nblocks) ? bsum[t] : 0;
    sm[t] = v;
    __syncthreads();
    for (int off = 1; off < 256; off <<= 1) {
        int x = (t >= off) ? sm[t - off] : 0;
        __syncthreads();
        sm[t] += x;
        __syncthreads();
    }
    if (t < nblocks) boff[t] = sm[t] - v;
    if (t == 255) row_ptr[N] = sm[255];
}

// per-(dst,type) segment cursors: cursor4[v][t] = row_ptr[v] + prefix(cnt4[v][0..t-1])
__global__ void k_scan_add(int* __restrict__ row_ptr, int* __restrict__ cursor4,
                           const int* __restrict__ boff, const int* __restrict__ cnt4, int N) {
    int i = blockIdx.x * 256 + threadIdx.x;
    if (i < N) {
        int r = row_ptr[i] + boff[blockIdx.x];
        row_ptr[i] = r;
        const int4 q = ((const int4*)cnt4)[i];
        int4 c;
        c.x = r;
        c.y = r + q.x;
        c.z = r + q.x + q.y;
        c.w = r + q.x + q.y + q.z;
        ((int4*)cursor4)[i] = c;
    }
}

// edges sorted by (dst, etype): segment pick in aggregate is wave-uniform scalar.
__global__ void k_scatter(const int* __restrict__ src, const int* __restrict__ dst,
                          const int* __restrict__ et, int* __restrict__ cursor4,
                          int* __restrict__ edge_pk, int E) {
    int i = blockIdx.x * 256 + threadIdx.x;
    if (i < E) {
        int p = atomicAdd(&cursor4[dst[i] * 4 + et[i]], 1);
        edge_pk[p] = src[i];
    }
}

// ---------- init h (fp16) into AH[:,128:256] ----------
__global__ void k_init_h(const float* __restrict__ feat, unsigned short* __restrict__ AH, int N) {
    int i = blockIdx.x * 256 + threadIdx.x;
    if (i < N * 128) {
        int v = i >> 7, d = i & 127;
        AH[(size_t)v * 256 + 128 + d] = f2hs(feat[i]);
    }
}

// ---------- weight prep: single fp16, n-major [Nout][K] ----------
__global__ void k_prep_wcat(const float* __restrict__ W, unsigned short* __restrict__ w) {
    int i = blockIdx.x * 256 + threadIdx.x;   // 4*128*128 = 65536
    if (i < 65536) {
        int t = i >> 14, o = (i >> 7) & 127, d = i & 127;
        w[o * 512 + t * 128 + d] = f2hs(W[i]);
    }
}

// r,z rows: Wrz[256][256], row j = [W_ih[j] | W_hh[j]]
__global__ void k_prep_wrz(const float* __restrict__ Wih, const float* __restrict__ Whh,
                           unsigned short* __restrict__ w) {
    int i = blockIdx.x * 256 + threadIdx.x;   // 256*256
    if (i < 256 * 256) {
        int j = i >> 8, k = i & 255;
        float v = (k < 128) ? Wih[j * 128 + k] : Whh[j * 128 + (k - 128)];
        w[i] = f2hs(v);
    }
}

// i_n rows: Win[128][128] = W_ih rows 256..383 ; h_n rows: Whn[128][128] = W_hh rows 256..383
__global__ void k_prep_wnh(const float* __restrict__ Wih, const float* __restrict__ Whh,
                           unsigned short* __restrict__ win, unsigned short* __restrict__ whn) {
    int i = blockIdx.x * 256 + threadIdx.x;   // 128*128
    if (i < 128 * 128) {
        int c = i >> 7, k = i & 127;
        win[i] = f2hs(Wih[(256 + c) * 128 + k]);
        whn[i] = f2hs(Whh[(256 + c) * 128 + k]);
    }
}

// ---------- per-step: aggregate h[src] by (dst, etype): S[v][t*128+d] ----------
// Simple 2-node/wave, 12-deep clamped batches, wave-uniform scalar segment
// tree. Measured-best form (954-956us total across R4/R5/R6). Attempts that
// measured WORSE and are permanently rejected: LDS ds_add atomics (R3: 9x
// slower, lgkm serialization), 2-deep SW pipeline (R8: +40% dur from rotation
// VALU overhead). Per-(lane,node,type) accumulation order = edge order.
__global__ __launch_bounds__(256) void k_aggregate(
    const int* __restrict__ row_ptr, const int* __restrict__ cnt4,
    const int* __restrict__ edge_pk,
    const unsigned short* __restrict__ AH, unsigned short* __restrict__ S, int N)
{
    const int wv = threadIdx.x >> 6;
    const int lane = threadIdx.x & 63;
    const int v0 = blockIdx.x * 8 + wv * 2;
    if (v0 >= N) return;
    const int v1 = v0 + 1;
    const bool has1 = (v1 < N);

    const int beg0 = __builtin_amdgcn_readfirstlane(row_ptr[v0]);
    const int end0 = __builtin_amdgcn_readfirstlane(row_ptr[v0 + 1]);
    const int end1 = has1 ? __builtin_amdgcn_readfirstlane(row_ptr[v1 + 1]) : end0;
    const int4 q0 = ((const int4*)cnt4)[v0];
    const int c1 = beg0 + __builtin_amdgcn_readfirstlane(q0.x);
    const int c2 = c1 + __builtin_amdgcn_readfirstlane(q0.y);
    const int c3 = c2 + __builtin_amdgcn_readfirstlane(q0.z);
    const int c4 = end0;
    int c5 = end0, c6 = end0, c7 = end0;
    if (has1) {
        const int4 q1 = ((const int4*)cnt4)[v1];
        c5 = end0 + __builtin_amdgcn_readfirstlane(q1.x);
        c6 = c5 + __builtin_amdgcn_readfirstlane(q1.y);
        c7 = c6 + __builtin_amdgcn_readfirstlane(q1.z);
    }

    float a0x=0,a0y=0,a1x=0,a1y=0,a2x=0,a2y=0,a3x=0,a3y=0;
    float a4x=0,a4y=0,a5x=0,a5y=0,a6x=0,a6y=0,a7x=0,a7y=0;
    const unsigned short* hbase = AH + 128 + lane * 2;

    for (int e = beg0; e < end1; e += 12) {
        int sp[12];
        unsigned int hv[12];
#pragma unroll
        for (int u = 0; u < 12; ++u) {
            int idx = e + u;
            if (idx > end1 - 1) idx = end1 - 1;
            sp[u] = edge_pk[idx];
        }
#pragma unroll
        for (int u = 0; u < 12; ++u)
            hv[u] = *(const unsigned int*)(hbase + (size_t)sp[u] * 256);
#pragma unroll
        for (int u = 0; u < 12; ++u) {
            const int idx = e + u;              // wave-uniform
            if (idx < end1) {
                H2 c; c.u = hv[u];
                float x0 = (float)c.h[0];
                float x1 = (float)c.h[1];
                if (idx < c4) {
                    if (idx < c2) { if (idx < c1) { a0x+=x0; a0y+=x1; } else { a1x+=x0; a1y+=x1; } }
                    else          { if (idx < c3) { a2x+=x0; a2y+=x1; } else { a3x+=x0; a3y+=x1; } }
                } else {
                    if (idx < c6) { if (idx < c5) { a4x+=x0; a4y+=x1; } else { a5x+=x0; a5y+=x1; } }
                    else          { if (idx < c7) { a6x+=x0; a6y+=x1; } else { a7x+=x0; a7y+=x1; } }
                }
            }
        }
    }

    unsigned int* Sp0 = (unsigned int*)&S[(size_t)v0 * 512];
    Sp0[lane]       = pack2h(a0x, a0y);
    Sp0[64 + lane]  = pack2h(a1x, a1y);
    Sp0[128 + lane] = pack2h(a2x, a2y);
    Sp0[192 + lane] = pack2h(a3x, a3y);
    if (has1) {
        unsigned int* Sp1 = (unsigned int*)&S[(size_t)v1 * 512];
        Sp1[lane]       = pack2h(a4x, a4y);
        Sp1[64 + lane]  = pack2h(a5x, a5y);
        Sp1[128 + lane] = pack2h(a6x, a6y);
        Sp1[192 + lane] = pack2h(a7x, a7y);
    }
}

// ---------- etype GEMM: C[64,128] tile, K=512, BK=64 as 2x32 panels, fp16 ----------
__global__ __launch_bounds__(256) void k_gemm0(
    const unsigned short* __restrict__ A, int M,
    const unsigned short* __restrict__ Bw,
    unsigned short* __restrict__ outAH, const int* __restrict__ cnt4,
    const float* __restrict__ b_et)
{
    __shared__ __align__(16) unsigned short As[2][64 * 32];
    __shared__ __align__(16) unsigned short Bs[2][128 * 32];
    const int tid  = threadIdx.x;
    const int lane = tid & 63;
    const int wv   = tid >> 6;
    const int wm   = (wv & 1) * 32;
    const int wn   = (wv >> 1) * 64;
    const int mBase = blockIdx.x * 64;
    const int srow = tid >> 2;          // 0..63
    const int sseg = (tid & 3) * 8;
    const int Ktot = 512;

    floatx4 acc[2][4];
#pragma unroll
    for (int i = 0; i < 2; ++i)
#pragma unroll
        for (int j = 0; j < 4; ++j) acc[i][j] = (floatx4){0.f, 0.f, 0.f, 0.f};

    int r0 = mBase + srow; if (r0 >= M) r0 = M - 1;

    for (int k0 = 0; k0 < Ktot; k0 += 64) {
        __syncthreads();
#pragma unroll
        for (int sub = 0; sub < 2; ++sub) {
            const int ko = k0 + sub * 32;
            load_lds16(A + (size_t)r0 * 512 + ko + sseg, &As[sub][srow * 32 + sseg]);
            const unsigned short* bw = Bw + (size_t)srow * Ktot + ko + sseg;
            load_lds16(bw,                     &Bs[sub][srow * 32 + sseg]);
            load_lds16(bw + (size_t)64 * Ktot, &Bs[sub][(srow + 64) * 32 + sseg]);
        }
        __syncthreads();
        const int kof = (lane >> 4) * 8;
        const int mr  = lane & 15;
#pragma unroll
        for (int p = 0; p < 2; ++p) {
            half8 af[2], bf[4];
#pragma unroll
            for (int i = 0; i < 2; ++i) af[i] = *(const half8*)&As[p][(wm + i * 16 + mr) * 32 + kof];
#pragma unroll
            for (int j = 0; j < 4; ++j) bf[j] = *(const half8*)&Bs[p][(wn + j * 16 + mr) * 32 + kof];
#pragma unroll
            for (int i = 0; i < 2; ++i)
#pragma unroll
                for (int j = 0; j < 4; ++j)
                    acc[i][j] = __builtin_amdgcn_mfma_f32_16x16x32_f16(af[i], bf[j], acc[i][j], 0, 0, 0);
        }
    }

    const int mr4 = (lane >> 4) * 4;
    const int nc  = lane & 15;
#pragma unroll
    for (int i = 0; i < 2; ++i) {
#pragma unroll
        for (int r = 0; r < 4; ++r) {
            int row = mBase + wm + i * 16 + mr4 + r;
            if (row < M) {
                int cx = cnt4[row * 4 + 0], cy = cnt4[row * 4 + 1];
                int cz = cnt4[row * 4 + 2], cw = cnt4[row * 4 + 3];
#pragma unroll
                for (int j = 0; j < 4; ++j) {
                    int col = wn + j * 16 + nc;
                    float val = acc[i][j][r]
                        + (float)cx * b_et[col]       + (float)cy * b_et[128 + col]
                        + (float)cz * b_et[256 + col] + (float)cw * b_et[384 + col];
                    outAH[(size_t)row * 256 + col] = f2hs(val);
                }
            }
        }
    }
}

// ---------- gates GEMM, zero-block-eliminated K-split, fp16, BM=64 ----------
// grid (mblocks64, 4): y=0,1 -> r,z cols (K=256); y=2 -> i_n (K=128, a-half);
// y=3 -> h_n (K=128, h-half). Fused gates+GRU kernel measured 80+us at 8%
// occupancy TWICE (R1 @ BM=128, R7 @ BM=64) -- split is structurally better:
// the 4 independent y-families overlap each other's barrier drains.
__global__ __launch_bounds__(256) void k_gemm1(
    const unsigned short* __restrict__ A, int M,
    const unsigned short* __restrict__ Wrz,
    const unsigned short* __restrict__ Win, const unsigned short* __restrict__ Whn,
    _Float16* __restrict__ G)
{
    __shared__ __align__(16) unsigned short As[2][64 * 32];
    __shared__ __align__(16) unsigned short Bs[2][128 * 32];
    const int tid  = threadIdx.x;
    const int lane = tid & 63;
    const int wv   = tid >> 6;
    const int wm   = (wv & 1) * 32;
    const int wn   = (wv >> 1) * 64;
    const int mBase = blockIdx.x * 64;
    const int y    = blockIdx.y;
    const int srow = tid >> 2;          // 0..63
    const int sseg = (tid & 3) * 8;

    const unsigned short* Bw;
    int Ktot, aOff, colBase;
    if (y < 2)      { Bw = Wrz + (size_t)y * 128 * 256; Ktot = 256; aOff = 0;   colBase = y * 128; }
    else if (y == 2){ Bw = Win; Ktot = 128; aOff = 0;   colBase = 256; }
    else            { Bw = Whn; Ktot = 128; aOff = 128; colBase = 384; }

    floatx4 acc[2][4];
#pragma unroll
    for (int i = 0; i < 2; ++i)
#pragma unroll
        for (int j = 0; j < 4; ++j) acc[i][j] = (floatx4){0.f, 0.f, 0.f, 0.f};

    int r0 = mBase + srow; if (r0 >= M) r0 = M - 1;

    for (int k0 = 0; k0 < Ktot; k0 += 64) {
        __syncthreads();
#pragma unroll
        for (int sub = 0; sub < 2; ++sub) {
            const int ko = k0 + sub * 32;
            load_lds16(A + (size_t)r0 * 256 + aOff + ko + sseg, &As[sub][srow * 32 + sseg]);
            const unsigned short* bw = Bw + (size_t)srow * Ktot + ko + sseg;
            load_lds16(bw,                     &Bs[sub][srow * 32 + sseg]);
            load_lds16(bw + (size_t)64 * Ktot, &Bs[sub][(srow + 64) * 32 + sseg]);
        }
        __syncthreads();
        const int kof = (lane >> 4) * 8;
        const int mr  = lane & 15;
#pragma unroll
        for (int p = 0; p < 2; ++p) {
            half8 af[2], bf[4];
#pragma unroll
            for (int i = 0; i < 2; ++i) af[i] = *(const half8*)&As[p][(wm + i * 16 + mr) * 32 + kof];
#pragma unroll
            for (int j = 0; j < 4; ++j) bf[j] = *(const half8*)&Bs[p][(wn + j * 16 + mr) * 32 + kof];
#pragma unroll
            for (int i = 0; i < 2; ++i)
#pragma unroll
                for (int j = 0; j < 4; ++j)
                    acc[i][j] = __builtin_amdgcn_mfma_f32_16x16x32_f16(af[i], bf[j], acc[i][j], 0, 0, 0);
        }
    }

    const int mr4 = (lane >> 4) * 4;
    const int nc  = lane & 15;
#pragma unroll
    for (int i = 0; i < 2; ++i) {
#pragma unroll
        for (int r = 0; r < 4; ++r) {
            int row = mBase + wm + i * 16 + mr4 + r;
            if (row < M) {
#pragma unroll
                for (int j = 0; j < 4; ++j) {
                    int col = colBase + wn + j * 16 + nc;
                    G[(size_t)row * 512 + col] = (_Float16)acc[i][j][r];
                }
            }
        }
    }
}

// ---------- GRU elementwise (fp16 G, 2 dims/thread) ----------
__global__ void k_gru(const _Float16* __restrict__ G, unsigned short* __restrict__ AH,
                      const float* __restrict__ b_ih, const float* __restrict__ b_hh, int N) {
    int i = blockIdx.x * 256 + threadIdx.x;
    if (i >= N * 64) return;
    int v = i >> 6, j = i & 63;          // pair index (2 dims)
    const unsigned int* g32 = (const unsigned int*)(G + (size_t)v * 512);
    H2 pr, pz, pn, ph;
    pr.u = g32[j];
    pz.u = g32[64 + j];
    pn.u = g32[128 + j];
    ph.u = g32[192 + j];
    H2 hv; hv.u = *(const unsigned int*)&AH[(size_t)v * 256 + 128 + j * 2];
    float outs[2];
#pragma unroll
    for (int q = 0; q < 2; ++q) {
        int d = j * 2 + q;
        float pre_r = (float)pr.h[q] + b_ih[d]       + b_hh[d];
        float pre_z = (float)pz.h[q] + b_ih[128 + d] + b_hh[128 + d];
        float i_n   = (float)pn.h[q] + b_ih[256 + d];
        float h_n   = (float)ph.h[q] + b_hh[256 + d];
        float r = 1.f / (1.f + __expf(-pre_r));
        float z = 1.f / (1.f + __expf(-pre_z));
        float n = tanhf(i_n + r * h_n);
        float h = (float)hv.h[q];
        outs[q] = (1.f - z) * n + z * h;
    }
    *(unsigned int*)&AH[(size_t)v * 256 + 128 + j * 2] = pack2h(outs[0], outs[1]);
}

// ---------- readout stage 1: per-node classifier dot (no atomics) ----------
__global__ void k_dotv(const unsigned short* __restrict__ AH, const float* __restrict__ cls_w,
                       float* __restrict__ dotv, int N) {
    int v = blockIdx.x * 4 + (threadIdx.x >> 6);
    int lane = threadIdx.x & 63;
    if (v >= N) return;
    H2 c; c.u = *(const unsigned int*)&AH[(size_t)v * 256 + 128 + lane * 2];
    float x = (float)c.h[0] * cls_w[lane * 2]
            + (float)c.h[1] * cls_w[lane * 2 + 1];
#pragma unroll
    for (int off = 32; off > 0; off >>= 1) x += __shfl_down(x, off);
    if (lane == 0) dotv[v] = x;
}

// ---------- readout stage 2: per-graph sum over sorted gids + sigmoid ----------
__global__ void k_gsum(const float* __restrict__ dotv, const int* __restrict__ gids,
                       const float* __restrict__ cls_b, float* __restrict__ out, int N) {
    int g = blockIdx.x;
    int t = threadIdx.x;   // 256
    int lo = 0, hi = N;
    while (lo < hi) { int m = (lo + hi) >> 1; if (gids[m] < g) lo = m + 1; else hi = m; }
    int s = lo;
    lo = 0; hi = N;
    while (lo < hi) { int m = (lo + hi) >> 1; if (gids[m] < g + 1) lo = m + 1; else hi = m; }
    int e = lo;
    float acc = 0.f;
    for (int v = s + t; v < e; v += 256) acc += dotv[v];
    __shared__ float red[256];
    red[t] = acc;
    __syncthreads();
    for (int off = 128; off > 0; off >>= 1) {
        if (t < off) red[t] += red[t + off];
        __syncthreads();
    }
    if (t == 0) out[g] = 1.f / (1.f + expf(-(red[0] + cls_b[0])));
}

// ---------- host ----------
extern "C" void kernel_launch(void* const* d_in, const int* in_sizes, int n_in,
                              void* d_out, int out_size, void* d_ws, size_t ws_size,
                              hipStream_t stream) {
    const float* features = (const float*)d_in[0];
    const int*   src      = (const int*)d_in[1];
    const int*   dst      = (const int*)d_in[2];
    const int*   etype    = (const int*)d_in[3];
    const int*   gids     = (const int*)d_in[4];
    const float* W_etype  = (const float*)d_in[5];
    const float* b_etype  = (const float*)d_in[6];
    const float* W_ih     = (const float*)d_in[7];
    const float* W_hh     = (const float*)d_in[8];
    const float* b_ih     = (const float*)d_in[9];
    const float* b_hh     = (const float*)d_in[10];
    const float* cls_w    = (const float*)d_in[11];
    const float* cls_b    = (const float*)d_in[12];
    const int N = in_sizes[0] / 128;
    const int E = in_sizes[1];
    float* out = (float*)d_out;

    char* ws = (char*)d_ws;
    size_t off = 0;
    auto alloc = [&](size_t bytes) -> void* {
        off = (off + 255) & ~(size_t)255;
        void* p = ws + off;
        off += bytes;
        return p;
    };
    unsigned short* AH  = (unsigned short*)alloc((size_t)N * 256 * 2); // [a | h] fp16
    unsigned short* S   = (unsigned short*)alloc((size_t)N * 512 * 2); // fp16
    _Float16*       G   = (_Float16*)alloc((size_t)N * 512 * 2);       // fp16 gates
    unsigned short* Wc  = (unsigned short*)alloc(128 * 512 * 2);
    unsigned short* Wrz = (unsigned short*)alloc(256 * 256 * 2);
    unsigned short* Win = (unsigned short*)alloc(128 * 128 * 2);
    unsigned short* Whn = (unsigned short*)alloc(128 * 128 * 2);
    int* row_ptr = (int*)alloc((size_t)(N + 1) * 4);
    int* cursor4 = (int*)alloc((size_t)N * 16);
    int* cnt4    = (int*)alloc((size_t)N * 16);
    int* edge_pk = (int*)alloc((size_t)E * 4);
    float* dotv  = (float*)alloc((size_t)N * 4);
    int* bsum    = (int*)alloc(256 * 4);
    int* boff    = (int*)alloc(256 * 4);
    (void)ws_size; (void)n_in;

    const int nscan = (N + 255) / 256;   // must be <= 256
    hipMemsetAsync(cnt4, 0, (size_t)N * 16, stream);
    k_hist<<<(E + 255) / 256, 256, 0, stream>>>(dst, etype, cnt4, E);
    k_scan_blk<<<nscan, 256, 0, stream>>>(cnt4, row_ptr, bsum, N);
    k_scan_top<<<1, 256, 0, stream>>>(bsum, boff, row_ptr, nscan, N);
    k_scan_add<<<nscan, 256, 0, stream>>>(row_ptr, cursor4, boff, cnt4, N);
    k_scatter<<<(E + 255) / 256, 256, 0, stream>>>(src, dst, etype, cursor4, edge_pk, E);
    k_init_h<<<(N * 128 + 255) / 256, 256, 0, stream>>>(features, AH, N);
    k_prep_wcat<<<65536 / 256, 256, 0, stream>>>(W_etype, Wc);
    k_prep_wrz<<<(256 * 256) / 256, 256, 0, stream>>>(W_ih, W_hh, Wrz);
    k_prep_wnh<<<(128 * 128) / 256, 256, 0, stream>>>(W_ih, W_hh, Win, Whn);

    const int mblocks64 = (N + 63) / 64;
    for (int s = 0; s < 8; ++s) {
        k_aggregate<<<(N + 7) / 8, 256, 0, stream>>>(row_ptr, cnt4, edge_pk, AH, S, N);
        k_gemm0<<<mblocks64, 256, 0, stream>>>(S, N, Wc, AH, cnt4, b_etype);
        dim3 g2(mblocks64, 4);
        k_gemm1<<<g2, 256, 0, stream>>>(AH, N, Wrz, Win, Whn, G);
        k_gru<<<(N * 64 + 255) / 256, 256, 0, stream>>>(G, AH, b_ih, b_hh, N);
    }
    k_dotv<<<(N + 3) / 4, 256, 0, stream>>>(AH, cls_w, dotv, N);
    k_gsum<<<out_size, 256, 0, stream>>>(dotv, gids, cls_b, out, N);
}

// Round 10
// 942.507 us; speedup vs baseline: 1.3169x; 1.0199x over previous
//
#include <hip/hip_runtime.h>

typedef __attribute__((ext_vector_type(4))) float floatx4;
typedef __attribute__((ext_vector_type(8))) _Float16 half8;

// ---------- fp16 helpers (RNE via _Float16 convert) ----------
union H2 { unsigned int u; _Float16 h[2]; };

__device__ __forceinline__ float hs2f(unsigned short u) {
    union { unsigned short u; _Float16 h; } c; c.u = u; return (float)c.h;
}
__device__ __forceinline__ unsigned short f2hs(float f) {
    union { unsigned short u; _Float16 h; } c; c.h = (_Float16)f; return c.u;
}
__device__ __forceinline__ unsigned int pack2h(float a, float b) {
    H2 c; c.h[0] = (_Float16)a; c.h[1] = (_Float16)b; return c.u;
}

// ---------- async global->LDS, 16B per lane ----------
__device__ __forceinline__ void load_lds16(const unsigned short* g, unsigned short* l) {
    __builtin_amdgcn_global_load_lds(
        (__attribute__((address_space(1))) void*)(g),
        (__attribute__((address_space(3))) void*)(l), 16, 0, 0);
}

// ---------- CSR build ----------
__global__ void k_hist(const int* __restrict__ dst, const int* __restrict__ et,
                       int* __restrict__ cnt4, int E) {
    int i = blockIdx.x * 256 + threadIdx.x;
    if (i < E) {
        atomicAdd(&cnt4[dst[i] * 4 + et[i]], 1);
    }
}

__global__ void k_scan_blk(const int* __restrict__ cnt4, int* __restrict__ row_ptr,
                           int* __restrict__ bsum, int N) {
    __shared__ int sm[256];
    int b = blockIdx.x, t = threadIdx.x, i = b * 256 + t;
    int v = 0;
    if (i < N) {
        const int4 q = ((const int4*)cnt4)[i];
        v = q.x + q.y + q.z + q.w;
    }
    sm[t] = v;
    __syncthreads();
    for (int off = 1; off < 256; off <<= 1) {
        int x = (t >= off) ? sm[t - off] : 0;
        __syncthreads();
        sm[t] += x;
        __syncthreads();
    }
    if (i < N) row_ptr[i] = sm[t] - v;
    if (t == 255) bsum[b] = sm[255];
}

__global__ void k_scan_top(int* __restrict__ bsum, int* __restrict__ boff,
                           int* __restrict__ row_ptr, int nblocks, int N) {
    __shared__ int sm[256];
    int t = threadIdx.x;
    int v = (t < nblocks) ? bsum[t] : 0;
    sm[t] = v;
    __syncthreads();
    for (int off = 1; off < 256; off <<= 1) {
        int x = (t >= off) ? sm[t - off] : 0;
        __syncthreads();
        sm[t] += x;
        __syncthreads();
    }
    if (t < nblocks) boff[t] = sm[t] - v;
    if (t == 255) row_ptr[N] = sm[255];
}

// per-(dst,type) segment cursors: cursor4[v][t] = row_ptr[v] + prefix(cnt4[v][0..t-1])
__global__ void k_scan_add(int* __restrict__ row_ptr, int* __restrict__ cursor4,
                           const int* __restrict__ boff, const int* __restrict__ cnt4, int N) {
    int i = blockIdx.x * 256 + threadIdx.x;
    if (i < N) {
        int r = row_ptr[i] + boff[blockIdx.x];
        row_ptr[i] = r;
        const int4 q = ((const int4*)cnt4)[i];
        int4 c;
        c.x = r;
        c.y = r + q.x;
        c.z = r + q.x + q.y;
        c.w = r + q.x + q.y + q.z;
        ((int4*)cursor4)[i] = c;
    }
}

// edges sorted by (dst, etype); payload = T-row id (et*N + src) so the
// aggregate needs NO per-edge type logic at all.
__global__ void k_scatter(const int* __restrict__ src, const int* __restrict__ dst,
                          const int* __restrict__ et, int* __restrict__ cursor4,
                          int* __restrict__ edge_pk, int E, int Nn) {
    int i = blockIdx.x * 256 + threadIdx.x;
    if (i < E) {
        int p = atomicAdd(&cursor4[dst[i] * 4 + et[i]], 1);
        edge_pk[p] = et[i] * Nn + src[i];
    }
}

// ---------- init h (fp16) into AH[:,128:256] ----------
__global__ void k_init_h(const float* __restrict__ feat, unsigned short* __restrict__ AH, int N) {
    int i = blockIdx.x * 256 + threadIdx.x;
    if (i < N * 128) {
        int v = i >> 7, d = i & 127;
        AH[(size_t)v * 256 + 128 + d] = f2hs(feat[i]);
    }
}

// ---------- weight prep ----------
// Wc2: fp16 cast of W_etype, layout [t][o][d] (natural order, n-major per type)
__global__ void k_prep_wc2(const float* __restrict__ W, unsigned short* __restrict__ w) {
    int i = blockIdx.x * 256 + threadIdx.x;   // 4*128*128 = 65536
    if (i < 65536) w[i] = f2hs(W[i]);
}

// r,z rows: Wrz[256][256], row j = [W_ih[j] | W_hh[j]]
__global__ void k_prep_wrz(const float* __restrict__ Wih, const float* __restrict__ Whh,
                           unsigned short* __restrict__ w) {
    int i = blockIdx.x * 256 + threadIdx.x;   // 256*256
    if (i < 256 * 256) {
        int j = i >> 8, k = i & 255;
        float v = (k < 128) ? Wih[j * 128 + k] : Whh[j * 128 + (k - 128)];
        w[i] = f2hs(v);
    }
}

// i_n rows: Win[128][128] = W_ih rows 256..383 ; h_n rows: Whn[128][128] = W_hh rows 256..383
__global__ void k_prep_wnh(const float* __restrict__ Wih, const float* __restrict__ Whh,
                           unsigned short* __restrict__ win, unsigned short* __restrict__ whn) {
    int i = blockIdx.x * 256 + threadIdx.x;   // 128*128
    if (i < 128 * 128) {
        int c = i >> 7, k = i & 127;
        win[i] = f2hs(Wih[(256 + c) * 128 + k]);
        whn[i] = f2hs(Whh[(256 + c) * 128 + k]);
    }
}

// ---------- per-step stage 1: T[t][v][:] = h[v] @ W_t^T (dense, no bias) ----------
// Transform-BEFORE-gather (the reference's own dataflow, legal by linearity).
// Same FLOPs as the old S-based gemm0, but eliminates the 102 MB/step S
// round-trip: agg2 gathers pre-transformed T rows straight into a.
// grid (mblocks64, 4): y = etype. BM=64, K=128 (h-half of AH).
__global__ __launch_bounds__(256) void k_gemm_pre(
    const unsigned short* __restrict__ AH, int M, int Nn,
    const unsigned short* __restrict__ Wc2,
    unsigned short* __restrict__ T)
{
    __shared__ __align__(16) unsigned short As[2][64 * 32];
    __shared__ __align__(16) unsigned short Bs[2][128 * 32];
    const int tid  = threadIdx.x;
    const int lane = tid & 63;
    const int wv   = tid >> 6;
    const int wm   = (wv & 1) * 32;
    const int wn   = (wv >> 1) * 64;
    const int mBase = blockIdx.x * 64;
    const int y    = blockIdx.y;
    const int srow = tid >> 2;          // 0..63
    const int sseg = (tid & 3) * 8;
    const int Ktot = 128;
    const unsigned short* Bw = Wc2 + (size_t)y * 128 * 128;

    floatx4 acc[2][4];
#pragma unroll
    for (int i = 0; i < 2; ++i)
#pragma unroll
        for (int j = 0; j < 4; ++j) acc[i][j] = (floatx4){0.f, 0.f, 0.f, 0.f};

    int r0 = mBase + srow; if (r0 >= M) r0 = M - 1;

    for (int k0 = 0; k0 < Ktot; k0 += 64) {
        __syncthreads();
#pragma unroll
        for (int sub = 0; sub < 2; ++sub) {
            const int ko = k0 + sub * 32;
            load_lds16(AH + (size_t)r0 * 256 + 128 + ko + sseg, &As[sub][srow * 32 + sseg]);
            const unsigned short* bw = Bw + (size_t)srow * Ktot + ko + sseg;
            load_lds16(bw,                     &Bs[sub][srow * 32 + sseg]);
            load_lds16(bw + (size_t)64 * Ktot, &Bs[sub][(srow + 64) * 32 + sseg]);
        }
        __syncthreads();
        const int kof = (lane >> 4) * 8;
        const int mr  = lane & 15;
#pragma unroll
        for (int p = 0; p < 2; ++p) {
            half8 af[2], bf[4];
#pragma unroll
            for (int i = 0; i < 2; ++i) af[i] = *(const half8*)&As[p][(wm + i * 16 + mr) * 32 + kof];
#pragma unroll
            for (int j = 0; j < 4; ++j) bf[j] = *(const half8*)&Bs[p][(wn + j * 16 + mr) * 32 + kof];
#pragma unroll
            for (int i = 0; i < 2; ++i)
#pragma unroll
                for (int j = 0; j < 4; ++j)
                    acc[i][j] = __builtin_amdgcn_mfma_f32_16x16x32_f16(af[i], bf[j], acc[i][j], 0, 0, 0);
        }
    }

    const int mr4 = (lane >> 4) * 4;
    const int nc  = lane & 15;
#pragma unroll
    for (int i = 0; i < 2; ++i) {
#pragma unroll
        for (int r = 0; r < 4; ++r) {
            int row = mBase + wm + i * 16 + mr4 + r;
            if (row < M) {
#pragma unroll
                for (int j = 0; j < 4; ++j) {
                    int col = wn + j * 16 + nc;
                    T[((size_t)y * Nn + row) * 128 + col] = f2hs(acc[i][j][r]);
                }
            }
        }
    }
}

// ---------- per-step stage 2: a[v] = sum_{edges into v} T[rowid(e)] + cnt-weighted bias ----------
// 2 nodes/wave, 12-deep clamped batches. No type logic: all 4 types sum into
// ONE accumulator pair (type is baked into the gathered T row). Only the node
// boundary (end0) remains -- wave-uniform scalar branch. ~6 inst/edge vs ~12
// in the old S-based aggregate. Writes a-half of AH directly (fp16).
__global__ __launch_bounds__(256) void k_aggregate2(
    const int* __restrict__ row_ptr, const int* __restrict__ cnt4,
    const int* __restrict__ edge_pk,
    const unsigned short* __restrict__ T, const float* __restrict__ b_et,
    unsigned short* __restrict__ AH, int N)
{
    const int wv = threadIdx.x >> 6;
    const int lane = threadIdx.x & 63;
    const int v0 = blockIdx.x * 8 + wv * 2;
    if (v0 >= N) return;
    const int v1 = v0 + 1;
    const bool has1 = (v1 < N);

    const int beg0 = __builtin_amdgcn_readfirstlane(row_ptr[v0]);
    const int end0 = __builtin_amdgcn_readfirstlane(row_ptr[v0 + 1]);
    const int end1 = has1 ? __builtin_amdgcn_readfirstlane(row_ptr[v1 + 1]) : end0;

    float a0x = 0, a0y = 0, a1x = 0, a1y = 0;
    const unsigned short* tbase = T + lane * 2;

    for (int e = beg0; e < end1; e += 12) {
        int sp[12];
        unsigned int hv[12];
#pragma unroll
        for (int u = 0; u < 12; ++u) {
            int idx = e + u;
            if (idx > end1 - 1) idx = end1 - 1;
            sp[u] = edge_pk[idx];
        }
#pragma unroll
        for (int u = 0; u < 12; ++u)
            hv[u] = *(const unsigned int*)(tbase + (size_t)sp[u] * 128);
#pragma unroll
        for (int u = 0; u < 12; ++u) {
            const int idx = e + u;              // wave-uniform
            if (idx < end1) {
                H2 c; c.u = hv[u];
                float x0 = (float)c.h[0];
                float x1 = (float)c.h[1];
                if (idx < end0) { a0x += x0; a0y += x1; }
                else            { a1x += x0; a1y += x1; }
            }
        }
    }

    // bias: reference adds b_et[t] per edge -> contribution = cnt[v][t] * b_t[d]
    const float2 b0 = *(const float2*)&b_et[0 * 128 + lane * 2];
    const float2 b1 = *(const float2*)&b_et[1 * 128 + lane * 2];
    const float2 b2 = *(const float2*)&b_et[2 * 128 + lane * 2];
    const float2 b3 = *(const float2*)&b_et[3 * 128 + lane * 2];
    {
        const int4 q = ((const int4*)cnt4)[v0];
        float bx = (float)q.x * b0.x + (float)q.y * b1.x + (float)q.z * b2.x + (float)q.w * b3.x;
        float by = (float)q.x * b0.y + (float)q.y * b1.y + (float)q.z * b2.y + (float)q.w * b3.y;
        *(unsigned int*)&AH[(size_t)v0 * 256 + lane * 2] = pack2h(a0x + bx, a0y + by);
    }
    if (has1) {
        const int4 q = ((const int4*)cnt4)[v1];
        float bx = (float)q.x * b0.x + (float)q.y * b1.x + (float)q.z * b2.x + (float)q.w * b3.x;
        float by = (float)q.x * b0.y + (float)q.y * b1.y + (float)q.z * b2.y + (float)q.w * b3.y;
        *(unsigned int*)&AH[(size_t)v1 * 256 + lane * 2] = pack2h(a1x + bx, a1y + by);
    }
}

// ---------- gates GEMM, zero-block-eliminated K-split, fp16, BM=64 ----------
// grid (mblocks64, 4): y=0,1 -> r,z cols (K=256); y=2 -> i_n (K=128, a-half);
// y=3 -> h_n (K=128, h-half). Fused gates+GRU kernel measured 80+us at 8%
// occupancy TWICE (R1/R7) -- split is structurally better.
__global__ __launch_bounds__(256) void k_gemm1(
    const unsigned short* __restrict__ A, int M,
    const unsigned short* __restrict__ Wrz,
    const unsigned short* __restrict__ Win, const unsigned short* __restrict__ Whn,
    _Float16* __restrict__ G)
{
    __shared__ __align__(16) unsigned short As[2][64 * 32];
    __shared__ __align__(16) unsigned short Bs[2][128 * 32];
    const int tid  = threadIdx.x;
    const int lane = tid & 63;
    const int wv   = tid >> 6;
    const int wm   = (wv & 1) * 32;
    const int wn   = (wv >> 1) * 64;
    const int mBase = blockIdx.x * 64;
    const int y    = blockIdx.y;
    const int srow = tid >> 2;          // 0..63
    const int sseg = (tid & 3) * 8;

    const unsigned short* Bw;
    int Ktot, aOff, colBase;
    if (y < 2)      { Bw = Wrz + (size_t)y * 128 * 256; Ktot = 256; aOff = 0;   colBase = y * 128; }
    else if (y == 2){ Bw = Win; Ktot = 128; aOff = 0;   colBase = 256; }
    else            { Bw = Whn; Ktot = 128; aOff = 128; colBase = 384; }

    floatx4 acc[2][4];
#pragma unroll
    for (int i = 0; i < 2; ++i)
#pragma unroll
        for (int j = 0; j < 4; ++j) acc[i][j] = (floatx4){0.f, 0.f, 0.f, 0.f};

    int r0 = mBase + srow; if (r0 >= M) r0 = M - 1;

    for (int k0 = 0; k0 < Ktot; k0 += 64) {
        __syncthreads();
#pragma unroll
        for (int sub = 0; sub < 2; ++sub) {
            const int ko = k0 + sub * 32;
            load_lds16(A + (size_t)r0 * 256 + aOff + ko + sseg, &As[sub][srow * 32 + sseg]);
            const unsigned short* bw = Bw + (size_t)srow * Ktot + ko + sseg;
            load_lds16(bw,                     &Bs[sub][srow * 32 + sseg]);
            load_lds16(bw + (size_t)64 * Ktot, &Bs[sub][(srow + 64) * 32 + sseg]);
        }
        __syncthreads();
        const int kof = (lane >> 4) * 8;
        const int mr  = lane & 15;
#pragma unroll
        for (int p = 0; p < 2; ++p) {
            half8 af[2], bf[4];
#pragma unroll
            for (int i = 0; i < 2; ++i) af[i] = *(const half8*)&As[p][(wm + i * 16 + mr) * 32 + kof];
#pragma unroll
            for (int j = 0; j < 4; ++j) bf[j] = *(const half8*)&Bs[p][(wn + j * 16 + mr) * 32 + kof];
#pragma unroll
            for (int i = 0; i < 2; ++i)
#pragma unroll
                for (int j = 0; j < 4; ++j)
                    acc[i][j] = __builtin_amdgcn_mfma_f32_16x16x32_f16(af[i], bf[j], acc[i][j], 0, 0, 0);
        }
    }

    const int mr4 = (lane >> 4) * 4;
    const int nc  = lane & 15;
#pragma unroll
    for (int i = 0; i < 2; ++i) {
#pragma unroll
        for (int r = 0; r < 4; ++r) {
            int row = mBase + wm + i * 16 + mr4 + r;
            if (row < M) {
#pragma unroll
                for (int j = 0; j < 4; ++j) {
                    int col = colBase + wn + j * 16 + nc;
                    G[(size_t)row * 512 + col] = (_Float16)acc[i][j][r];
                }
            }
        }
    }
}

// ---------- GRU elementwise (fp16 G, 2 dims/thread) ----------
__global__ void k_gru(const _Float16* __restrict__ G, unsigned short* __restrict__ AH,
                      const float* __restrict__ b_ih, const float* __restrict__ b_hh, int N) {
    int i = blockIdx.x * 256 + threadIdx.x;
    if (i >= N * 64) return;
    int v = i >> 6, j = i & 63;          // pair index (2 dims)
    const unsigned int* g32 = (const unsigned int*)(G + (size_t)v * 512);
    H2 pr, pz, pn, ph;
    pr.u = g32[j];
    pz.u = g32[64 + j];
    pn.u = g32[128 + j];
    ph.u = g32[192 + j];
    H2 hv; hv.u = *(const unsigned int*)&AH[(size_t)v * 256 + 128 + j * 2];
    float outs[2];
#pragma unroll
    for (int q = 0; q < 2; ++q) {
        int d = j * 2 + q;
        float pre_r = (float)pr.h[q] + b_ih[d]       + b_hh[d];
        float pre_z = (float)pz.h[q] + b_ih[128 + d] + b_hh[128 + d];
        float i_n   = (float)pn.h[q] + b_ih[256 + d];
        float h_n   = (float)ph.h[q] + b_hh[256 + d];
        float r = 1.f / (1.f + __expf(-pre_r));
        float z = 1.f / (1.f + __expf(-pre_z));
        float n = tanhf(i_n + r * h_n);
        float h = (float)hv.h[q];
        outs[q] = (1.f - z) * n + z * h;
    }
    *(unsigned int*)&AH[(size_t)v * 256 + 128 + j * 2] = pack2h(outs[0], outs[1]);
}

// ---------- readout stage 1: per-node classifier dot (no atomics) ----------
__global__ void k_dotv(const unsigned short* __restrict__ AH, const float* __restrict__ cls_w,
                       float* __restrict__ dotv, int N) {
    int v = blockIdx.x * 4 + (threadIdx.x >> 6);
    int lane = threadIdx.x & 63;
    if (v >= N) return;
    H2 c; c.u = *(const unsigned int*)&AH[(size_t)v * 256 + 128 + lane * 2];
    float x = (float)c.h[0] * cls_w[lane * 2]
            + (float)c.h[1] * cls_w[lane * 2 + 1];
#pragma unroll
    for (int off = 32; off > 0; off >>= 1) x += __shfl_down(x, off);
    if (lane == 0) dotv[v] = x;
}

// ---------- readout stage 2: per-graph sum over sorted gids + sigmoid ----------
__global__ void k_gsum(const float* __restrict__ dotv, const int* __restrict__ gids,
                       const float* __restrict__ cls_b, float* __restrict__ out, int N) {
    int g = blockIdx.x;
    int t = threadIdx.x;   // 256
    int lo = 0, hi = N;
    while (lo < hi) { int m = (lo + hi) >> 1; if (gids[m] < g) lo = m + 1; else hi = m; }
    int s = lo;
    lo = 0; hi = N;
    while (lo < hi) { int m = (lo + hi) >> 1; if (gids[m] < g + 1) lo = m + 1; else hi = m; }
    int e = lo;
    float acc = 0.f;
    for (int v = s + t; v < e; v += 256) acc += dotv[v];
    __shared__ float red[256];
    red[t] = acc;
    __syncthreads();
    for (int off = 128; off > 0; off >>= 1) {
        if (t < off) red[t] += red[t + off];
        __syncthreads();
    }
    if (t == 0) out[g] = 1.f / (1.f + expf(-(red[0] + cls_b[0])));
}

// ---------- host ----------
extern "C" void kernel_launch(void* const* d_in, const int* in_sizes, int n_in,
                              void* d_out, int out_size, void* d_ws, size_t ws_size,
                              hipStream_t stream) {
    const float* features = (const float*)d_in[0];
    const int*   src      = (const int*)d_in[1];
    const int*   dst      = (const int*)d_in[2];
    const int*   etype    = (const int*)d_in[3];
    const int*   gids     = (const int*)d_in[4];
    const float* W_etype  = (const float*)d_in[5];
    const float* b_etype  = (const float*)d_in[6];
    const float* W_ih     = (const float*)d_in[7];
    const float* W_hh     = (const float*)d_in[8];
    const float* b_ih     = (const float*)d_in[9];
    const float* b_hh     = (const float*)d_in[10];
    const float* cls_w    = (const float*)d_in[11];
    const float* cls_b    = (const float*)d_in[12];
    const int N = in_sizes[0] / 128;
    const int E = in_sizes[1];
    float* out = (float*)d_out;

    char* ws = (char*)d_ws;
    size_t off = 0;
    auto alloc = [&](size_t bytes) -> void* {
        off = (off + 255) & ~(size_t)255;
        void* p = ws + off;
        off += bytes;
        return p;
    };
    unsigned short* AH  = (unsigned short*)alloc((size_t)N * 256 * 2); // [a | h] fp16
    unsigned short* T   = (unsigned short*)alloc((size_t)4 * N * 128 * 2); // T[t][v][128] fp16
    _Float16*       G   = (_Float16*)alloc((size_t)N * 512 * 2);       // fp16 gates
    unsigned short* Wc2 = (unsigned short*)alloc(4 * 128 * 128 * 2);
    unsigned short* Wrz = (unsigned short*)alloc(256 * 256 * 2);
    unsigned short* Win = (unsigned short*)alloc(128 * 128 * 2);
    unsigned short* Whn = (unsigned short*)alloc(128 * 128 * 2);
    int* row_ptr = (int*)alloc((size_t)(N + 1) * 4);
    int* cursor4 = (int*)alloc((size_t)N * 16);
    int* cnt4    = (int*)alloc((size_t)N * 16);
    int* edge_pk = (int*)alloc((size_t)E * 4);
    float* dotv  = (float*)alloc((size_t)N * 4);
    int* bsum    = (int*)alloc(256 * 4);
    int* boff    = (int*)alloc(256 * 4);
    (void)ws_size; (void)n_in;

    const int nscan = (N + 255) / 256;   // must be <= 256
    hipMemsetAsync(cnt4, 0, (size_t)N * 16, stream);
    k_hist<<<(E + 255) / 256, 256, 0, stream>>>(dst, etype, cnt4, E);
    k_scan_blk<<<nscan, 256, 0, stream>>>(cnt4, row_ptr, bsum, N);
    k_scan_top<<<1, 256, 0, stream>>>(bsum, boff, row_ptr, nscan, N);
    k_scan_add<<<nscan, 256, 0, stream>>>(row_ptr, cursor4, boff, cnt4, N);
    k_scatter<<<(E + 255) / 256, 256, 0, stream>>>(src, dst, etype, cursor4, edge_pk, E, N);
    k_init_h<<<(N * 128 + 255) / 256, 256, 0, stream>>>(features, AH, N);
    k_prep_wc2<<<65536 / 256, 256, 0, stream>>>(W_etype, Wc2);
    k_prep_wrz<<<(256 * 256) / 256, 256, 0, stream>>>(W_ih, W_hh, Wrz);
    k_prep_wnh<<<(128 * 128) / 256, 256, 0, stream>>>(W_ih, W_hh, Win, Whn);

    const int mblocks64 = (N + 63) / 64;
    for (int s = 0; s < 8; ++s) {
        dim3 gp(mblocks64, 4);
        k_gemm_pre<<<gp, 256, 0, stream>>>(AH, N, N, Wc2, T);
        k_aggregate2<<<(N + 7) / 8, 256, 0, stream>>>(row_ptr, cnt4, edge_pk, T, b_etype, AH, N);
        dim3 g2(mblocks64, 4);
        k_gemm1<<<g2, 256, 0, stream>>>(AH, N, Wrz, Win, Whn, G);
        k_gru<<<(N * 64 + 255) / 256, 256, 0, stream>>>(G, AH, b_ih, b_hh, N);
    }
    k_dotv<<<(N + 3) / 4, 256, 0, stream>>>(AH, cls_w, dotv, N);
    k_gsum<<<out_size, 256, 0, stream>>>(dotv, gids, cls_b, out, N);
}

// Round 11
// 815.216 us; speedup vs baseline: 1.5225x; 1.1561x over previous
//
#include <hip/hip_runtime.h>

typedef __attribute__((ext_vector_type(4))) float floatx4;
typedef __attribute__((ext_vector_type(8))) _Float16 half8;

// ---------- fp16 helpers (RNE via _Float16 convert) ----------
union H2 { unsigned int u; _Float16 h[2]; };

__device__ __forceinline__ float hs2f(unsigned short u) {
    union { unsigned short u; _Float16 h; } c; c.u = u; return (float)c.h;
}
__device__ __forceinline__ unsigned short f2hs(float f) {
    union { unsigned short u; _Float16 h; } c; c.h = (_Float16)f; return c.u;
}
__device__ __forceinline__ unsigned int pack2h(float a, float b) {
    H2 c; c.h[0] = (_Float16)a; c.h[1] = (_Float16)b; return c.u;
}

// ---------- async global->LDS, 16B per lane ----------
__device__ __forceinline__ void load_lds16(const unsigned short* g, unsigned short* l) {
    __builtin_amdgcn_global_load_lds(
        (__attribute__((address_space(1))) void*)(g),
        (__attribute__((address_space(3))) void*)(l), 16, 0, 0);
}

// ---------- CSR build ----------
__global__ void k_hist(const int* __restrict__ dst, const int* __restrict__ et,
                       int* __restrict__ cnt4, int E) {
    int i = blockIdx.x * 256 + threadIdx.x;
    if (i < E) {
        atomicAdd(&cnt4[dst[i] * 4 + et[i]], 1);
    }
}

__global__ void k_scan_blk(const int* __restrict__ cnt4, int* __restrict__ row_ptr,
                           int* __restrict__ bsum, int N) {
    __shared__ int sm[256];
    int b = blockIdx.x, t = threadIdx.x, i = b * 256 + t;
    int v = 0;
    if (i < N) {
        const int4 q = ((const int4*)cnt4)[i];
        v = q.x + q.y + q.z + q.w;
    }
    sm[t] = v;
    __syncthreads();
    for (int off = 1; off < 256; off <<= 1) {
        int x = (t >= off) ? sm[t - off] : 0;
        __syncthreads();
        sm[t] += x;
        __syncthreads();
    }
    if (i < N) row_ptr[i] = sm[t] - v;
    if (t == 255) bsum[b] = sm[255];
}

__global__ void k_scan_top(int* __restrict__ bsum, int* __restrict__ boff,
                           int* __restrict__ row_ptr, int nblocks, int N) {
    __shared__ int sm[256];
    int t = threadIdx.x;
    int v = (t < nblocks) ? bsum[t] : 0;
    sm[t] = v;
    __syncthreads();
    for (int off = 1; off < 256; off <<= 1) {
        int x = (t >= off) ? sm[t - off] : 0;
        __syncthreads();
        sm[t] += x;
        __syncthreads();
    }
    if (t < nblocks) boff[t] = sm[t] - v;
    if (t == 255) row_ptr[N] = sm[255];
}

// per-(dst,type) segment cursors: cursor4[v][t] = row_ptr[v] + prefix(cnt4[v][0..t-1])
__global__ void k_scan_add(int* __restrict__ row_ptr, int* __restrict__ cursor4,
                           const int* __restrict__ boff, const int* __restrict__ cnt4, int N) {
    int i = blockIdx.x * 256 + threadIdx.x;
    if (i < N) {
        int r = row_ptr[i] + boff[blockIdx.x];
        row_ptr[i] = r;
        const int4 q = ((const int4*)cnt4)[i];
        int4 c;
        c.x = r;
        c.y = r + q.x;
        c.z = r + q.x + q.y;
        c.w = r + q.x + q.y + q.z;
        ((int4*)cursor4)[i] = c;
    }
}

// edges sorted by (dst, etype); payload = T-row id (et*N + src) so the
// aggregate needs NO per-edge type logic at all.
__global__ void k_scatter(const int* __restrict__ src, const int* __restrict__ dst,
                          const int* __restrict__ et, int* __restrict__ cursor4,
                          int* __restrict__ edge_pk, int E, int Nn) {
    int i = blockIdx.x * 256 + threadIdx.x;
    if (i < E) {
        int p = atomicAdd(&cursor4[dst[i] * 4 + et[i]], 1);
        edge_pk[p] = et[i] * Nn + src[i];
    }
}

// ---------- init h (fp16) into AH[:,128:256] ----------
__global__ void k_init_h(const float* __restrict__ feat, unsigned short* __restrict__ AH, int N) {
    int i = blockIdx.x * 256 + threadIdx.x;
    if (i < N * 128) {
        int v = i >> 7, d = i & 127;
        AH[(size_t)v * 256 + 128 + d] = f2hs(feat[i]);
    }
}

// ---------- weight prep ----------
// Wc2: fp16 cast of W_etype, layout [t][o][d] (natural order, n-major per type)
__global__ void k_prep_wc2(const float* __restrict__ W, unsigned short* __restrict__ w) {
    int i = blockIdx.x * 256 + threadIdx.x;   // 4*128*128 = 65536
    if (i < 65536) w[i] = f2hs(W[i]);
}

// r,z rows: Wrz[256][256], row j = [W_ih[j] | W_hh[j]]  (rows 0..127 = r, 128..255 = z)
__global__ void k_prep_wrz(const float* __restrict__ Wih, const float* __restrict__ Whh,
                           unsigned short* __restrict__ w) {
    int i = blockIdx.x * 256 + threadIdx.x;   // 256*256
    if (i < 256 * 256) {
        int j = i >> 8, k = i & 255;
        float v = (k < 128) ? Wih[j * 128 + k] : Whh[j * 128 + (k - 128)];
        w[i] = f2hs(v);
    }
}

// i_n rows: Win[128][128] = W_ih rows 256..383 ; h_n rows: Whn[128][128] = W_hh rows 256..383
__global__ void k_prep_wnh(const float* __restrict__ Wih, const float* __restrict__ Whh,
                           unsigned short* __restrict__ win, unsigned short* __restrict__ whn) {
    int i = blockIdx.x * 256 + threadIdx.x;   // 128*128
    if (i < 128 * 128) {
        int c = i >> 7, k = i & 127;
        win[i] = f2hs(Wih[(256 + c) * 128 + k]);
        whn[i] = f2hs(Whh[(256 + c) * 128 + k]);
    }
}

// ---------- per-step stage 1: T[t][v][:] = h[v] @ W_t^T (dense, no bias) ----------
// Transform-BEFORE-gather (legal by linearity): eliminates the old S round-trip.
// grid (mblocks64, 4): y = etype. BM=64, K=128 (h-half of AH).
__global__ __launch_bounds__(256) void k_gemm_pre(
    const unsigned short* __restrict__ AH, int M, int Nn,
    const unsigned short* __restrict__ Wc2,
    unsigned short* __restrict__ T)
{
    __shared__ __align__(16) unsigned short As[2][64 * 32];
    __shared__ __align__(16) unsigned short Bs[2][128 * 32];
    const int tid  = threadIdx.x;
    const int lane = tid & 63;
    const int wv   = tid >> 6;
    const int wm   = (wv & 1) * 32;
    const int wn   = (wv >> 1) * 64;
    const int mBase = blockIdx.x * 64;
    const int y    = blockIdx.y;
    const int srow = tid >> 2;          // 0..63
    const int sseg = (tid & 3) * 8;
    const int Ktot = 128;
    const unsigned short* Bw = Wc2 + (size_t)y * 128 * 128;

    floatx4 acc[2][4];
#pragma unroll
    for (int i = 0; i < 2; ++i)
#pragma unroll
        for (int j = 0; j < 4; ++j) acc[i][j] = (floatx4){0.f, 0.f, 0.f, 0.f};

    int r0 = mBase + srow; if (r0 >= M) r0 = M - 1;

    for (int k0 = 0; k0 < Ktot; k0 += 64) {
        __syncthreads();
#pragma unroll
        for (int sub = 0; sub < 2; ++sub) {
            const int ko = k0 + sub * 32;
            load_lds16(AH + (size_t)r0 * 256 + 128 + ko + sseg, &As[sub][srow * 32 + sseg]);
            const unsigned short* bw = Bw + (size_t)srow * Ktot + ko + sseg;
            load_lds16(bw,                     &Bs[sub][srow * 32 + sseg]);
            load_lds16(bw + (size_t)64 * Ktot, &Bs[sub][(srow + 64) * 32 + sseg]);
        }
        __syncthreads();
        const int kof = (lane >> 4) * 8;
        const int mr  = lane & 15;
#pragma unroll
        for (int p = 0; p < 2; ++p) {
            half8 af[2], bf[4];
#pragma unroll
            for (int i = 0; i < 2; ++i) af[i] = *(const half8*)&As[p][(wm + i * 16 + mr) * 32 + kof];
#pragma unroll
            for (int j = 0; j < 4; ++j) bf[j] = *(const half8*)&Bs[p][(wn + j * 16 + mr) * 32 + kof];
#pragma unroll
            for (int i = 0; i < 2; ++i)
#pragma unroll
                for (int j = 0; j < 4; ++j)
                    acc[i][j] = __builtin_amdgcn_mfma_f32_16x16x32_f16(af[i], bf[j], acc[i][j], 0, 0, 0);
        }
    }

    const int mr4 = (lane >> 4) * 4;
    const int nc  = lane & 15;
#pragma unroll
    for (int i = 0; i < 2; ++i) {
#pragma unroll
        for (int r = 0; r < 4; ++r) {
            int row = mBase + wm + i * 16 + mr4 + r;
            if (row < M) {
#pragma unroll
                for (int j = 0; j < 4; ++j) {
                    int col = wn + j * 16 + nc;
                    T[((size_t)y * Nn + row) * 128 + col] = f2hs(acc[i][j][r]);
                }
            }
        }
    }
}

// ---------- per-step stage 2: a[v] = sum_{edges into v} T[rowid(e)] + cnt-weighted bias ----------
// 2 nodes/wave, 12-deep clamped batches, no per-edge type logic.
__global__ __launch_bounds__(256) void k_aggregate2(
    const int* __restrict__ row_ptr, const int* __restrict__ cnt4,
    const int* __restrict__ edge_pk,
    const unsigned short* __restrict__ T, const float* __restrict__ b_et,
    unsigned short* __restrict__ AH, int N)
{
    const int wv = threadIdx.x >> 6;
    const int lane = threadIdx.x & 63;
    const int v0 = blockIdx.x * 8 + wv * 2;
    if (v0 >= N) return;
    const int v1 = v0 + 1;
    const bool has1 = (v1 < N);

    const int beg0 = __builtin_amdgcn_readfirstlane(row_ptr[v0]);
    const int end0 = __builtin_amdgcn_readfirstlane(row_ptr[v0 + 1]);
    const int end1 = has1 ? __builtin_amdgcn_readfirstlane(row_ptr[v1 + 1]) : end0;

    float a0x = 0, a0y = 0, a1x = 0, a1y = 0;
    const unsigned short* tbase = T + lane * 2;

    for (int e = beg0; e < end1; e += 12) {
        int sp[12];
        unsigned int hv[12];
#pragma unroll
        for (int u = 0; u < 12; ++u) {
            int idx = e + u;
            if (idx > end1 - 1) idx = end1 - 1;
            sp[u] = edge_pk[idx];
        }
#pragma unroll
        for (int u = 0; u < 12; ++u)
            hv[u] = *(const unsigned int*)(tbase + (size_t)sp[u] * 128);
#pragma unroll
        for (int u = 0; u < 12; ++u) {
            const int idx = e + u;              // wave-uniform
            if (idx < end1) {
                H2 c; c.u = hv[u];
                float x0 = (float)c.h[0];
                float x1 = (float)c.h[1];
                if (idx < end0) { a0x += x0; a0y += x1; }
                else            { a1x += x0; a1y += x1; }
            }
        }
    }

    // bias: reference adds b_et[t] per edge -> contribution = cnt[v][t] * b_t[d]
    const float2 b0 = *(const float2*)&b_et[0 * 128 + lane * 2];
    const float2 b1 = *(const float2*)&b_et[1 * 128 + lane * 2];
    const float2 b2 = *(const float2*)&b_et[2 * 128 + lane * 2];
    const float2 b3 = *(const float2*)&b_et[3 * 128 + lane * 2];
    {
        const int4 q = ((const int4*)cnt4)[v0];
        float bx = (float)q.x * b0.x + (float)q.y * b1.x + (float)q.z * b2.x + (float)q.w * b3.x;
        float by = (float)q.x * b0.y + (float)q.y * b1.y + (float)q.z * b2.y + (float)q.w * b3.y;
        *(unsigned int*)&AH[(size_t)v0 * 256 + lane * 2] = pack2h(a0x + bx, a0y + by);
    }
    if (has1) {
        const int4 q = ((const int4*)cnt4)[v1];
        float bx = (float)q.x * b0.x + (float)q.y * b1.x + (float)q.z * b2.x + (float)q.w * b3.x;
        float by = (float)q.x * b0.y + (float)q.y * b1.y + (float)q.z * b2.y + (float)q.w * b3.y;
        *(unsigned int*)&AH[(size_t)v1 * 256 + lane * 2] = pack2h(a1x + bx, a1y + by);
    }
}

// ---------- fused gates+GRU, SINGLE K-loop (structurally unlike dead R1/R7 kernel) ----------
// grid (mblocks64, 4 col-slabs of 32 gate-dims). Each block computes r,z,i_n,h_n
// pre-activations for a 64-row x 32-dim slab in ONE K=256 loop: a-half chunks
// accumulate {r,z,i_n}, h-half chunks {r,z,h_n} (ahalf = wave-uniform scalar).
// 8 barrier-pairs/block (same as working gemm1 y=0/1), 3128 blocks (same grid),
// LDS 20KB, acc 8 floatx4. Gates stay f32 in regs -> GRU epilogue -> h written
// to the PING-PONG buffer AHn (avoids read/write race on h). Eliminates the
// 102 MB/step G round-trip + k_gru. R1/R7's failure (3 serial K-phases, 16
// drains, 140-200 VGPR) is structurally absent here.
__global__ __launch_bounds__(256) void k_gates1(
    const unsigned short* __restrict__ AHc,      // read [a|h]
    unsigned short* __restrict__ AHn,            // write h-half
    int M,
    const unsigned short* __restrict__ Wr,       // [128][256] (= Wrz rows 0..127)
    const unsigned short* __restrict__ Wz,       // [128][256] (= Wrz rows 128..255)
    const unsigned short* __restrict__ Wi,       // [128][128]
    const unsigned short* __restrict__ Wh,       // [128][128]
    const float* __restrict__ b_ih, const float* __restrict__ b_hh)
{
    __shared__ __align__(16) unsigned short As[2][64 * 32];       // 8 KB
    __shared__ __align__(16) unsigned short Bs[2][3][32 * 32];    // 12 KB
    const int tid  = threadIdx.x;
    const int lane = tid & 63;
    const int wv   = tid >> 6;
    const int wm   = (wv & 1) * 32;     // wave row offset (2x2 wave grid)
    const int wn   = (wv >> 1) * 16;    // wave col offset within 32-slab
    const int mBase = blockIdx.x * 64;
    const int slab = blockIdx.y;        // 0..3 -> gate dims slab*32..+32
    const int srow = tid >> 2;          // 0..63
    const int sseg = (tid & 3) * 8;
    const int kof  = (lane >> 4) * 8;
    const int mr   = lane & 15;

    int r0 = mBase + srow; if (r0 >= M) r0 = M - 1;

    floatx4 acc[2][4];                  // [rowfrag][gate: r,z,i_n,h_n]
#pragma unroll
    for (int i = 0; i < 2; ++i)
#pragma unroll
        for (int g = 0; g < 4; ++g) acc[i][g] = (floatx4){0.f, 0.f, 0.f, 0.f};

    const int t2   = tid & 127;
    const int brow = slab * 32 + (t2 >> 2);     // B panel row (gate dim)
    const int bseg = (t2 & 3) * 8;

    for (int k0 = 0; k0 < 256; k0 += 64) {
        const bool ahalf = (k0 < 128);
        __syncthreads();
#pragma unroll
        for (int sub = 0; sub < 2; ++sub) {
            const int ks = k0 + sub * 32;
            // A: 64 rows x 32 K of [a|h]
            load_lds16(AHc + (size_t)r0 * 256 + ks + sseg, &As[sub][srow * 32 + sseg]);
            // B pass 1: waves 0,1 -> panel r ; waves 2,3 -> panel z
            const unsigned short* bsrc = (tid < 128)
                ? Wr + (size_t)brow * 256 + ks + bseg
                : Wz + (size_t)brow * 256 + ks + bseg;
            load_lds16(bsrc, &Bs[sub][0][0] + tid * 8);
            // B pass 2: waves 0,1 -> panel {i_n | h_n}
            if (tid < 128) {
                const unsigned short* b3 = ahalf
                    ? Wi + (size_t)brow * 128 + ks + bseg
                    : Wh + (size_t)brow * 128 + (ks - 128) + bseg;
                load_lds16(b3, &Bs[sub][2][0] + tid * 8);
            }
        }
        __syncthreads();
#pragma unroll
        for (int p = 0; p < 2; ++p) {
            half8 af[2], br_, bz_, b3_;
#pragma unroll
            for (int i = 0; i < 2; ++i) af[i] = *(const half8*)&As[p][(wm + i * 16 + mr) * 32 + kof];
            br_ = *(const half8*)&Bs[p][0][(wn + mr) * 32 + kof];
            bz_ = *(const half8*)&Bs[p][1][(wn + mr) * 32 + kof];
            b3_ = *(const half8*)&Bs[p][2][(wn + mr) * 32 + kof];
#pragma unroll
            for (int i = 0; i < 2; ++i) {
                acc[i][0] = __builtin_amdgcn_mfma_f32_16x16x32_f16(af[i], br_, acc[i][0], 0, 0, 0);
                acc[i][1] = __builtin_amdgcn_mfma_f32_16x16x32_f16(af[i], bz_, acc[i][1], 0, 0, 0);
                if (ahalf) acc[i][2] = __builtin_amdgcn_mfma_f32_16x16x32_f16(af[i], b3_, acc[i][2], 0, 0, 0);
                else       acc[i][3] = __builtin_amdgcn_mfma_f32_16x16x32_f16(af[i], b3_, acc[i][3], 0, 0, 0);
            }
        }
    }

    // ---- GRU epilogue: h' = (1-z)*n + z*h, n = tanh(i_n + r*h_n) ----
    const int mr4 = (lane >> 4) * 4;
    const int nc  = lane & 15;
    const int col = slab * 32 + wn + nc;        // gate dim 0..127
    const float b_r  = b_ih[col]       + b_hh[col];
    const float b_z  = b_ih[128 + col] + b_hh[128 + col];
    const float b_in = b_ih[256 + col];
    const float b_hn = b_hh[256 + col];
#pragma unroll
    for (int i = 0; i < 2; ++i) {
#pragma unroll
        for (int r = 0; r < 4; ++r) {
            int row = mBase + wm + i * 16 + mr4 + r;
            if (row < M) {
                float rv = acc[i][0][r] + b_r;
                float zv = acc[i][1][r] + b_z;
                float iv = acc[i][2][r] + b_in;
                float hv = acc[i][3][r] + b_hn;
                rv = 1.f / (1.f + __expf(-rv));
                zv = 1.f / (1.f + __expf(-zv));
                float nv = tanhf(iv + rv * hv);
                float h = hs2f(AHc[(size_t)row * 256 + 128 + col]);
                AHn[(size_t)row * 256 + 128 + col] = f2hs((1.f - zv) * nv + zv * h);
            }
        }
    }
}

// ---------- readout stage 1: per-node classifier dot (no atomics) ----------
__global__ void k_dotv(const unsigned short* __restrict__ AH, const float* __restrict__ cls_w,
                       float* __restrict__ dotv, int N) {
    int v = blockIdx.x * 4 + (threadIdx.x >> 6);
    int lane = threadIdx.x & 63;
    if (v >= N) return;
    H2 c; c.u = *(const unsigned int*)&AH[(size_t)v * 256 + 128 + lane * 2];
    float x = (float)c.h[0] * cls_w[lane * 2]
            + (float)c.h[1] * cls_w[lane * 2 + 1];
#pragma unroll
    for (int off = 32; off > 0; off >>= 1) x += __shfl_down(x, off);
    if (lane == 0) dotv[v] = x;
}

// ---------- readout stage 2: per-graph sum over sorted gids + sigmoid ----------
__global__ void k_gsum(const float* __restrict__ dotv, const int* __restrict__ gids,
                       const float* __restrict__ cls_b, float* __restrict__ out, int N) {
    int g = blockIdx.x;
    int t = threadIdx.x;   // 256
    int lo = 0, hi = N;
    while (lo < hi) { int m = (lo + hi) >> 1; if (gids[m] < g) lo = m + 1; else hi = m; }
    int s = lo;
    lo = 0; hi = N;
    while (lo < hi) { int m = (lo + hi) >> 1; if (gids[m] < g + 1) lo = m + 1; else hi = m; }
    int e = lo;
    float acc = 0.f;
    for (int v = s + t; v < e; v += 256) acc += dotv[v];
    __shared__ float red[256];
    red[t] = acc;
    __syncthreads();
    for (int off = 128; off > 0; off >>= 1) {
        if (t < off) red[t] += red[t + off];
        __syncthreads();
    }
    if (t == 0) out[g] = 1.f / (1.f + expf(-(red[0] + cls_b[0])));
}

// ---------- host ----------
extern "C" void kernel_launch(void* const* d_in, const int* in_sizes, int n_in,
                              void* d_out, int out_size, void* d_ws, size_t ws_size,
                              hipStream_t stream) {
    const float* features = (const float*)d_in[0];
    const int*   src      = (const int*)d_in[1];
    const int*   dst      = (const int*)d_in[2];
    const int*   etype    = (const int*)d_in[3];
    const int*   gids     = (const int*)d_in[4];
    const float* W_etype  = (const float*)d_in[5];
    const float* b_etype  = (const float*)d_in[6];
    const float* W_ih     = (const float*)d_in[7];
    const float* W_hh     = (const float*)d_in[8];
    const float* b_ih     = (const float*)d_in[9];
    const float* b_hh     = (const float*)d_in[10];
    const float* cls_w    = (const float*)d_in[11];
    const float* cls_b    = (const float*)d_in[12];
    const int N = in_sizes[0] / 128;
    const int E = in_sizes[1];
    float* out = (float*)d_out;

    char* ws = (char*)d_ws;
    size_t off = 0;
    auto alloc = [&](size_t bytes) -> void* {
        off = (off + 255) & ~(size_t)255;
        void* p = ws + off;
        off += bytes;
        return p;
    };
    unsigned short* A0  = (unsigned short*)alloc((size_t)N * 256 * 2); // [a | h] fp16 ping
    unsigned short* A1  = (unsigned short*)alloc((size_t)N * 256 * 2); // [a | h] fp16 pong
    unsigned short* T   = (unsigned short*)alloc((size_t)4 * N * 128 * 2); // T[t][v][128] fp16
    unsigned short* Wc2 = (unsigned short*)alloc(4 * 128 * 128 * 2);
    unsigned short* Wrz = (unsigned short*)alloc(256 * 256 * 2);
    unsigned short* Win = (unsigned short*)alloc(128 * 128 * 2);
    unsigned short* Whn = (unsigned short*)alloc(128 * 128 * 2);
    int* row_ptr = (int*)alloc((size_t)(N + 1) * 4);
    int* cursor4 = (int*)alloc((size_t)N * 16);
    int* cnt4    = (int*)alloc((size_t)N * 16);
    int* edge_pk = (int*)alloc((size_t)E * 4);
    float* dotv  = (float*)alloc((size_t)N * 4);
    int* bsum    = (int*)alloc(256 * 4);
    int* boff    = (int*)alloc(256 * 4);
    (void)ws_size; (void)n_in;

    const int nscan = (N + 255) / 256;   // must be <= 256
    hipMemsetAsync(cnt4, 0, (size_t)N * 16, stream);
    k_hist<<<(E + 255) / 256, 256, 0, stream>>>(dst, etype, cnt4, E);
    k_scan_blk<<<nscan, 256, 0, stream>>>(cnt4, row_ptr, bsum, N);
    k_scan_top<<<1, 256, 0, stream>>>(bsum, boff, row_ptr, nscan, N);
    k_scan_add<<<nscan, 256, 0, stream>>>(row_ptr, cursor4, boff, cnt4, N);
    k_scatter<<<(E + 255) / 256, 256, 0, stream>>>(src, dst, etype, cursor4, edge_pk, E, N);
    k_init_h<<<(N * 128 + 255) / 256, 256, 0, stream>>>(features, A0, N);
    k_prep_wc2<<<65536 / 256, 256, 0, stream>>>(W_etype, Wc2);
    k_prep_wrz<<<(256 * 256) / 256, 256, 0, stream>>>(W_ih, W_hh, Wrz);
    k_prep_wnh<<<(128 * 128) / 256, 256, 0, stream>>>(W_ih, W_hh, Win, Whn);

    const int mblocks64 = (N + 63) / 64;
    unsigned short* cur = A0;
    unsigned short* nxt = A1;
    for (int s = 0; s < 8; ++s) {
        dim3 gp(mblocks64, 4);
        k_gemm_pre<<<gp, 256, 0, stream>>>(cur, N, N, Wc2, T);
        k_aggregate2<<<(N + 7) / 8, 256, 0, stream>>>(row_ptr, cnt4, edge_pk, T, b_etype, cur, N);
        dim3 gg(mblocks64, 4);
        k_gates1<<<gg, 256, 0, stream>>>(cur, nxt, N,
                                         Wrz, Wrz + (size_t)128 * 256,
                                         Win, Whn, b_ih, b_hh);
        unsigned short* tmp = cur; cur = nxt; nxt = tmp;
    }
    k_dotv<<<(N + 3) / 4, 256, 0, stream>>>(cur, cls_w, dotv, N);
    k_gsum<<<out_size, 256, 0, stream>>>(dotv, gids, cls_b, out, N);
}